// Round 5
// baseline (521.300 us; speedup 1.0000x reference)
//
#include <hip/hip_runtime.h>

typedef unsigned int u32;
typedef unsigned short u16;

#define ROWS  524288   // B*N
#define BROWS 4096     // B
#define EPS   1e-5f

// ---- stats: 4 shards of 1024 floats each (atomic contention /4); consumers sum shards ----
#define S_U   0     // 4 sum + 4 ssq
#define S_O1  8     // 32 sum + 32 ssq
#define S_A1  72
#define S_O12 136
#define S_A2  200
#define S_X   264
#define S_X1  328
#define S_X2  392
#define S_X3  456
#define SHARD 1024  // floats

// ---- folded-weight block FW (float offsets) ----
#define FW1P 0
#define C1P  128
#define FW1O 160
#define C1O  288
#define FW2P 320
#define C2P  1344
#define FW2O 1376
#define C2O  2400
#define FW3P 2432
#define C3P  3456
#define FW3O 3488
#define C3O  4512

__device__ __forceinline__ float bl(u32 u){ return __uint_as_float(u << 16); }
__device__ __forceinline__ float bh(u32 u){ return __uint_as_float(u & 0xFFFF0000u); }
__device__ __forceinline__ float b2f(u16 h){ return __uint_as_float(((u32)h) << 16); }
__device__ __forceinline__ u16 f2b(float f){
  u32 u = __float_as_uint(f);
  return (u16)((u + 0x7FFFu + ((u >> 16) & 1u)) >> 16);   // RNE
}
__device__ __forceinline__ float tanh_fast(float x){
  float e = __expf(2.0f * x);
  return 1.0f - 2.0f * __builtin_amdgcn_rcpf(e + 1.0f);
}
__device__ __forceinline__ float sumsh(const float* __restrict__ S, int off){
  return S[off] + S[SHARD+off] + S[2*SHARD+off] + S[3*SHARD+off];
}

template<bool F32>
__device__ __forceinline__ float rdp(const void* p, int i){
  if (F32) return ((const float*)p)[i];
  return b2f(((const u16*)p)[i]);
}
template<bool F32>
__device__ __forceinline__ void load_u4(const void* u, int r, float* f){
  if (F32){
    float4 v = ((const float4*)u)[r];
    f[0]=v.x; f[1]=v.y; f[2]=v.z; f[3]=v.w;
  } else {
    uint2 v = ((const uint2*)u)[r];
    f[0]=bl(v.x); f[1]=bh(v.x); f[2]=bl(v.y); f[3]=bh(v.y);
  }
}

// ---------------- dtype detection ----------------
__global__ void k_detect(const u16* __restrict__ u, int* __restrict__ flag){
  int t = threadIdx.x;   // 64
  int bad = 0;
  for (int i = t*4; i < t*4+4; ++i){
    int e = (u[i] >> 7) & 0xFF;
    bad += (e >= 0x90) ? 1 : 0;
  }
#pragma unroll
  for (int off = 32; off >= 1; off >>= 1) bad += __shfl_down(bad, off);
  if (t == 0) *flag = (bad >= 4) ? 1 : 0;
}

// ---------------- stats of u (4 cols) ----------------
template<bool F32>
__device__ __forceinline__ void stats_u_body(const void* __restrict__ u, float* __restrict__ S){
  int tid = blockIdx.x*blockDim.x + threadIdx.x;
  int nt  = gridDim.x*blockDim.x;
  float s[4]={0,0,0,0}, q[4]={0,0,0,0};
  for (int r = tid; r < ROWS; r += nt){
    float f[4]; load_u4<F32>(u, r, f);
#pragma unroll
    for (int k=0;k<4;++k){ s[k]+=f[k]; q[k]+=f[k]*f[k]; }
  }
#pragma unroll
  for (int off=32; off>=1; off>>=1){
#pragma unroll
    for (int k=0;k<4;++k){ s[k]+=__shfl_down(s[k],off); q[k]+=__shfl_down(q[k],off); }
  }
  if ((threadIdx.x & 63) == 0){
    float* Sh = S + (blockIdx.x & 3)*SHARD;
#pragma unroll
    for (int k=0;k<4;++k){ atomicAdd(&Sh[S_U+k], s[k]); atomicAdd(&Sh[S_U+4+k], q[k]); }
  }
}
__global__ __launch_bounds__(256,4) void k_stats_u(const void* __restrict__ u, float* __restrict__ S,
                                                   const int* __restrict__ flag){
  if (*flag) stats_u_body<true>(u,S); else stats_u_body<false>(u,S);
}

// ---------------- pass1: stats of o1, a1 (lane owns column) ----------------
template<bool F32>
__device__ __forceinline__ void pass1_body(
    const void* __restrict__ u,
    const void* pg1, const void* pb1, const void* pw1,
    const void* og1, const void* ob1, const void* ow1,
    float* __restrict__ S, float* lds)
{
  int tid = blockIdx.x*blockDim.x + threadIdx.x;
  int j = tid & 31;
  int g = tid >> 5;
  int ng = (gridDim.x*blockDim.x) >> 5;
  float wp[4], wo[4], cp=0.f, co=0.f;
#pragma unroll
  for (int k=0;k<4;++k){
    float m    = sumsh(S, S_U+k)   * (1.0f/ROWS);
    float var  = sumsh(S, S_U+4+k) * (1.0f/ROWS) - m*m;
    float rstd = rsqrtf(var + EPS);
    float sp = rdp<F32>(pg1,k)*rstd, so = rdp<F32>(og1,k)*rstd;
    float Wp = rdp<F32>(pw1, j*4+k), Wo = rdp<F32>(ow1, j*4+k);
    wp[k]=Wp*sp; wo[k]=Wo*so;
    cp += Wp*(rdp<F32>(pb1,k)-m*sp);
    co += Wo*(rdp<F32>(ob1,k)-m*so);
  }
  float so1=0,qo1=0,sa1=0,qa1=0;
  for (int r=g; r<ROWS; r+=ng){
    float f[4]; load_u4<F32>(u,r,f);
    float vp = cp + wp[0]*f[0]+wp[1]*f[1]+wp[2]*f[2]+wp[3]*f[3];
    float vo = co + wo[0]*f[0]+wo[1]*f[1]+wo[2]*f[2]+wo[3]*f[3];
    float tp = tanh_fast(vp), to = tanh_fast(vo);
    so1+=tp; qo1+=tp*tp; sa1+=to; qa1+=to*to;
  }
  so1+=__shfl_down(so1,32); qo1+=__shfl_down(qo1,32);
  sa1+=__shfl_down(sa1,32); qa1+=__shfl_down(qa1,32);
  int wv = threadIdx.x>>6, ln = threadIdx.x&63;
  if (ln<32){ float* p = lds + (wv*32+ln)*4; p[0]=so1; p[1]=qo1; p[2]=sa1; p[3]=qa1; }
  __syncthreads();
  if (threadIdx.x < 32){
    float a=0,b=0,c=0,d=0;
#pragma unroll
    for (int w=0;w<4;++w){ const float* p = lds + (w*32+threadIdx.x)*4; a+=p[0]; b+=p[1]; c+=p[2]; d+=p[3]; }
    float* Sh = S + (blockIdx.x & 3)*SHARD;
    atomicAdd(&Sh[S_O1+threadIdx.x], a); atomicAdd(&Sh[S_O1+32+threadIdx.x], b);
    atomicAdd(&Sh[S_A1+threadIdx.x], c); atomicAdd(&Sh[S_A1+32+threadIdx.x], d);
  }
}
__global__ __launch_bounds__(256,4) void k_pass1(
    const void* u, const void* pg1, const void* pb1, const void* pw1,
    const void* og1, const void* ob1, const void* ow1,
    float* S, const int* __restrict__ flag)
{
  __shared__ float lds[4*32*4];
  if (*flag) pass1_body<true>(u,pg1,pb1,pw1,og1,ob1,ow1,S,lds);
  else       pass1_body<false>(u,pg1,pb1,pw1,og1,ob1,ow1,S,lds);
}

// ---------------- BN+Linear fold ----------------
template<bool F32, int KDIM>
__device__ __forceinline__ void fold_one(const float* __restrict__ S, int off, float invN,
    const void* g, const void* b, const void* W,
    float* __restrict__ Wf, float* __restrict__ cf, int j)
{
  float c = 0.f;
#pragma unroll
  for (int k=0;k<KDIM;++k){
    float m    = sumsh(S, off+k)*invN;
    float var  = sumsh(S, off+KDIM+k)*invN - m*m;
    float rstd = rsqrtf(var+EPS);
    float s  = rdp<F32>(g,k)*rstd;
    float Wv = rdp<F32>(W, j*KDIM+k);
    Wf[k*32+j] = Wv*s;
    c += Wv*(rdp<F32>(b,k)-m*s);
  }
  cf[j] = c;
}

__global__ void k_foldL1(const float* __restrict__ S, float* __restrict__ FW,
    const void* pg1, const void* pb1, const void* pw1,
    const void* og1, const void* ob1, const void* ow1,
    const int* __restrict__ flag)
{
  int t = threadIdx.x;   // 64
  int j = t & 31;
  int isf = *flag;
  if (t < 32){
    if (isf) fold_one<true ,4>(S, S_U, 1.0f/ROWS, pg1,pb1,pw1, FW+FW1P, FW+C1P, j);
    else     fold_one<false,4>(S, S_U, 1.0f/ROWS, pg1,pb1,pw1, FW+FW1P, FW+C1P, j);
  } else {
    if (isf) fold_one<true ,4>(S, S_U, 1.0f/ROWS, og1,ob1,ow1, FW+FW1O, FW+C1O, j);
    else     fold_one<false,4>(S, S_U, 1.0f/ROWS, og1,ob1,ow1, FW+FW1O, FW+C1O, j);
  }
}

__global__ void k_foldL(const float* __restrict__ S, int offA, int offB, float* __restrict__ FW,
    int offWp, int offCp, int offWo, int offCo,
    const void* gp, const void* bp, const void* Wp,
    const void* go, const void* bo, const void* Wo,
    const int* __restrict__ flag)
{
  int t = threadIdx.x;   // 64
  int j = t & 31;
  int isf = *flag;
  if (t < 32){
    if (isf) fold_one<true ,32>(S, offA, 1.0f/ROWS, gp,bp,Wp, FW+offWp, FW+offCp, j);
    else     fold_one<false,32>(S, offA, 1.0f/ROWS, gp,bp,Wp, FW+offWp, FW+offCp, j);
  } else {
    if (isf) fold_one<true ,32>(S, offB, 1.0f/ROWS, go,bo,Wo, FW+offWo, FW+offCo, j);
    else     fold_one<false,32>(S, offB, 1.0f/ROWS, go,bo,Wo, FW+offWo, FW+offCo, j);
  }
}

// ---------------- pass2 (merged): stats of o12 AND a2; 1 row/thread, j-tiled by 8, FULLY UNROLLED ----------------
// R4 bug: un-unrolled t-loops made o1[]/acc[] runtime-indexed -> scratch (WRITE_SIZE 123 MB).
// All tile loops are now #pragma unroll: every array index is compile-time -> VGPRs only.
template<bool F32, bool PHI>
__device__ __forceinline__ void pass2_chain(const float* f, const float* __restrict__ FW,
                                            float* __restrict__ outv)
{
  const float* F1 = FW + (PHI?FW1P:FW1O);
  const float* C1 = FW + (PHI?C1P :C1O );
  const float* F2 = FW + (PHI?FW2P:FW2O);
  const float* C2 = FW + (PHI?C2P :C2O );
  float o1[32];
#pragma unroll
  for (int j=0;j<32;++j)
    o1[j] = tanh_fast(C1[j] + f[0]*F1[j] + f[1]*F1[32+j] + f[2]*F1[64+j] + f[3]*F1[96+j]);
#pragma unroll
  for (int t=0;t<4;++t){
    float acc[8];
#pragma unroll
    for (int i=0;i<8;++i) acc[i] = C2[t*8+i];
#pragma unroll
    for (int k=0;k<32;++k){
      float xk = o1[k];
#pragma unroll
      for (int i=0;i<8;++i) acc[i] = fmaf(F2[k*32+t*8+i], xk, acc[i]);
    }
#pragma unroll
    for (int i=0;i<8;++i){
      float v = tanh_fast(acc[i]);
      if (PHI) v += o1[t*8+i];
      outv[t*8+i] = v;
    }
  }
}

__device__ __forceinline__ void pass2_reduce(const float* __restrict__ vals, float* lds, float* lds2,
                                             float* __restrict__ S, int offS, int shard)
{
  int tid = threadIdx.x;
#pragma unroll
  for (int j=0;j<32;++j) lds[tid*33+j] = vals[j];
  __syncthreads();
  {
    int j = tid & 31, seg = tid >> 5;
    float s=0.f, q=0.f;
    for (int q2=0;q2<32;++q2){
      float v = lds[(seg*32+q2)*33 + j];
      s += v; q = fmaf(v,v,q);
    }
    lds2[seg*32+j] = s;
    lds2[256 + seg*32+j] = q;
  }
  __syncthreads();
  if (tid < 64){
    int j = tid & 31; bool isq = tid >= 32;
    const float* src = lds2 + (isq?256:0);
    float tot=0.f;
#pragma unroll
    for (int sg=0;sg<8;++sg) tot += src[sg*32+j];
    atomicAdd(&S[shard*SHARD + offS + (isq?32:0) + j], tot);
  }
  __syncthreads();
}

template<bool F32>
__device__ __forceinline__ void pass2_body(const void* __restrict__ u,
    const float* __restrict__ FW, float* __restrict__ S, float* lds, float* lds2)
{
  int r = blockIdx.x*256 + threadIdx.x;
  int shard = blockIdx.x & 3;
  float f[4]; load_u4<F32>(u,r,f);
  float v[32];
  pass2_chain<F32,true >(f, FW, v);
  pass2_reduce(v, lds, lds2, S, S_O12, shard);
  pass2_chain<F32,false>(f, FW, v);
  pass2_reduce(v, lds, lds2, S, S_A2, shard);
}
__global__ __launch_bounds__(256) __attribute__((amdgpu_waves_per_eu(4,4)))
void k_pass2(const void* __restrict__ u, const float* __restrict__ FW, float* __restrict__ S,
             const int* __restrict__ flag){
  __shared__ float lds[256*33];
  __shared__ float lds2[512];
  if (*flag) pass2_body<true >(u,FW,S,lds,lds2);
  else       pass2_body<false>(u,FW,S,lds,lds2);
}

// ---------------- pass3: 1 row/thread, FULLY UNROLLED; fused stats of x ----------------
template<bool F32>
__device__ __forceinline__ void pass3_body(const void* __restrict__ u, const int* __restrict__ mask,
    const float* __restrict__ FW, float* __restrict__ x, float* __restrict__ S,
    float* red, float* red2)
{
  int n = threadIdx.x;                 // 256: two 128-neighbor groups
  int r = blockIdx.x*256 + n;
  float f[4]; load_u4<F32>(u,r,f);
  float A[32], T[32];

  // ---- omega: a1 (A) -> a2 (T) -> logits (A) -> softmax -> at stashed in LDS ----
#pragma unroll
  for (int j=0;j<32;++j)
    A[j] = tanh_fast(FW[C1O+j] + f[0]*FW[FW1O+j] + f[1]*FW[FW1O+32+j] + f[2]*FW[FW1O+64+j] + f[3]*FW[FW1O+96+j]);
#pragma unroll
  for (int t=0;t<4;++t){
    float acc[8];
#pragma unroll
    for (int i=0;i<8;++i) acc[i] = FW[C2O+t*8+i];
#pragma unroll
    for (int k=0;k<32;++k){ float xk=A[k];
#pragma unroll
      for (int i=0;i<8;++i) acc[i] = fmaf(FW[FW2O+k*32+t*8+i], xk, acc[i]); }
#pragma unroll
    for (int i=0;i<8;++i) T[t*8+i] = tanh_fast(acc[i]);      // a2
  }
#pragma unroll
  for (int t=0;t<4;++t){
    float acc[8];
#pragma unroll
    for (int i=0;i<8;++i) acc[i] = FW[C3O+t*8+i];
#pragma unroll
    for (int k=0;k<32;++k){ float xk=T[k];
#pragma unroll
      for (int i=0;i<8;++i) acc[i] = fmaf(FW[FW3O+k*32+t*8+i], xk, acc[i]); }
#pragma unroll
    for (int i=0;i<8;++i) A[t*8+i] = acc[i];                 // logits
  }
  float mx = A[0];
#pragma unroll
  for (int j=1;j<32;++j) mx = fmaxf(mx, A[j]);
  float sum = 0.f;
#pragma unroll
  for (int j=0;j<32;++j){ float e = __expf(A[j]-mx); A[j]=e; sum+=e; }
  float inv = __builtin_amdgcn_rcpf(sum);
  bool mz = (mask[r] == 0);
#pragma unroll
  for (int j=0;j<32;++j){
    float at = A[j]*inv;
    if (mz) at = -__builtin_inff();
    red[n*33+j] = at;                  // own slot, no sync needed
  }

  // ---- phi: o1 (A) -> o12 (T) -> xm (A) ----
#pragma unroll
  for (int j=0;j<32;++j)
    A[j] = tanh_fast(FW[C1P+j] + f[0]*FW[FW1P+j] + f[1]*FW[FW1P+32+j] + f[2]*FW[FW1P+64+j] + f[3]*FW[FW1P+96+j]);
#pragma unroll
  for (int t=0;t<4;++t){
    float acc[8];
#pragma unroll
    for (int i=0;i<8;++i) acc[i] = FW[C2P+t*8+i];
#pragma unroll
    for (int k=0;k<32;++k){ float xk=A[k];
#pragma unroll
      for (int i=0;i<8;++i) acc[i] = fmaf(FW[FW2P+k*32+t*8+i], xk, acc[i]); }
#pragma unroll
    for (int i=0;i<8;++i) T[t*8+i] = A[t*8+i] + tanh_fast(acc[i]);   // o12
  }
#pragma unroll
  for (int t=0;t<4;++t){
    float acc[8];
#pragma unroll
    for (int i=0;i<8;++i) acc[i] = FW[C3P+t*8+i];
#pragma unroll
    for (int k=0;k<32;++k){ float xk=T[k];
#pragma unroll
      for (int i=0;i<8;++i) acc[i] = fmaf(FW[FW3P+k*32+t*8+i], xk, acc[i]); }
#pragma unroll
    for (int i=0;i<8;++i) A[t*8+i] = T[t*8+i] + tanh_fast(acc[i]);   // xm
  }

  // multiply by stashed attention, pool over 128 neighbors (2 groups per block)
#pragma unroll
  for (int j=0;j<32;++j){ A[j] *= red[n*33+j]; red[n*33+j] = A[j]; }
  __syncthreads();
  {
    int jj = n & 31, c = (n >> 5) & 3, half = n >> 7;
    float s2 = 0.f;
    for (int q2=0;q2<32;++q2) s2 += red[(half*128 + c*32 + q2)*33 + jj];
    red2[n] = s2;
  }
  __syncthreads();
  if (n < 64){
    int half = n >> 5, j = n & 31;
    float v = red2[half*128+j] + red2[half*128+32+j] + red2[half*128+64+j] + red2[half*128+96+j];
    x[(blockIdx.x*2 + half)*32 + j] = v;
    float* Sh = S + (blockIdx.x & 3)*SHARD;
    atomicAdd(&Sh[S_X+j], v);          // fused stats of x
    atomicAdd(&Sh[S_X+32+j], v*v);
  }
}
__global__ __launch_bounds__(256) __attribute__((amdgpu_waves_per_eu(4,4)))
void k_pass3(const void* __restrict__ u, const int* __restrict__ mask, const float* __restrict__ FW,
             float* __restrict__ x, float* __restrict__ S, const int* __restrict__ flag){
  __shared__ float red[256*33];
  __shared__ float red2[256];
  if (*flag) pass3_body<true >(u,mask,FW,x,S,red,red2);
  else       pass3_body<false>(u,mask,FW,x,S,red,red2);
}

// ---------------- block-wide column reduce (blockDim==256) ----------------
__device__ __forceinline__ void block_reduce32(const float* vals, float* lds, float* __restrict__ dst){
  int t = threadIdx.x;
#pragma unroll
  for (int j=0;j<32;++j) lds[t*33+j] = vals[j];
  __syncthreads();
  if (t < 32){
    float tot=0.f;
    for (int q2=0;q2<256;++q2) tot += lds[q2*33+t];
    atomicAdd(&dst[t], tot);
  }
  __syncthreads();
}

// ---------------- theta layer ----------------
template<bool F32>
__device__ __forceinline__ void theta_body(const float* __restrict__ X, float* __restrict__ S, int offin,
    const void* g, const void* bt, const void* W, float* __restrict__ Y, int offout, float* lds)
{
  int r = blockIdx.x*blockDim.x + threadIdx.x;   // 4096 rows exactly
  float xn[32];
#pragma unroll
  for (int k=0;k<32;++k){
    float m    = sumsh(S, offin+k)    * (1.0f/BROWS);
    float var  = sumsh(S, offin+32+k) * (1.0f/BROWS) - m*m;
    float rstd = rsqrtf(var + EPS);
    xn[k] = (X[(size_t)r*32+k] - m) * (rdp<F32>(g,k)*rstd) + rdp<F32>(bt,k);
  }
  float out[32];
#pragma unroll
  for (int j=0;j<32;++j){
    float acc = 0.f;
#pragma unroll
    for (int k=0;k<32;++k) acc = fmaf(rdp<F32>(W, j*32+k), xn[k], acc);
    out[j] = tanh_fast(acc);
    Y[(size_t)r*32+j] = out[j];
  }
  float* Sh = S + (blockIdx.x & 3)*SHARD;
  block_reduce32(out, lds, Sh+offout);
#pragma unroll
  for (int j=0;j<32;++j) out[j] *= out[j];
  block_reduce32(out, lds, Sh+offout+32);
}
__global__ __launch_bounds__(256) __attribute__((amdgpu_waves_per_eu(4,4)))
void k_theta(const float* X, float* S, int offin,
    const void* g, const void* bt, const void* W, float* Y, int offout, const int* __restrict__ flag){
  __shared__ float lds[256*33];
  if (*flag) theta_body<true >(X,S,offin,g,bt,W,Y,offout,lds);
  else       theta_body<false>(X,S,offin,g,bt,W,Y,offout,lds);
}

// ---------------- final layer ----------------
template<bool F32>
__device__ __forceinline__ void theta4_body(const float* __restrict__ X, const float* __restrict__ S, int offin,
    const void* g, const void* bt, const void* w4, const void* b4, void* out)
{
  int r = blockIdx.x*blockDim.x + threadIdx.x;
  float acc = rdp<F32>(b4, 0);
#pragma unroll
  for (int k=0;k<32;++k){
    float m    = sumsh(S, offin+k)    * (1.0f/BROWS);
    float var  = sumsh(S, offin+32+k) * (1.0f/BROWS) - m*m;
    float rstd = rsqrtf(var + EPS);
    float xn = (X[(size_t)r*32+k] - m) * (rdp<F32>(g,k)*rstd) + rdp<F32>(bt,k);
    acc = fmaf(rdp<F32>(w4,k), xn, acc);
  }
  if (F32) ((float*)out)[r] = acc;
  else     ((u16*)out)[r]  = f2b(acc);
}
__global__ __launch_bounds__(256) void k_theta4(const float* X, const float* S, int offin,
    const void* g, const void* bt, const void* w4, const void* b4, void* out, const int* __restrict__ flag){
  if (*flag) theta4_body<true >(X,S,offin,g,bt,w4,b4,out);
  else       theta4_body<false>(X,S,offin,g,bt,w4,b4,out);
}

extern "C" void kernel_launch(void* const* d_in, const int* in_sizes, int n_in,
                              void* d_out, int out_size, void* d_ws, size_t ws_size,
                              hipStream_t stream)
{
  const void* u    = d_in[0];
  const int*  mask = (const int*)d_in[1];
  const void *pg1=d_in[2],  *pb1=d_in[3],  *pw1=d_in[4];
  const void *pg2=d_in[5],  *pb2=d_in[6],  *pw2=d_in[7];
  const void *pg3=d_in[8],  *pb3=d_in[9],  *pw3=d_in[10];
  const void *og1=d_in[11], *ob1=d_in[12], *ow1=d_in[13];
  const void *og2=d_in[14], *ob2=d_in[15], *ow2=d_in[16];
  const void *og3=d_in[17], *ob3=d_in[18], *ow3=d_in[19];
  const void *tg1=d_in[20], *tb1=d_in[21], *tw1=d_in[22];
  const void *tg2=d_in[23], *tb2=d_in[24], *tw2=d_in[25];
  const void *tg3=d_in[26], *tb3=d_in[27], *tw3=d_in[28];
  const void *tg4=d_in[29], *tb4=d_in[30], *tw4=d_in[31], *tbb4=d_in[32];

  char* ws = (char*)d_ws;
  int*   flag = (int*)ws;                    // byte 0
  float* S    = (float*)(ws + 1024);         // 4 shards x 1024 floats = 16 KB
  float* FW   = (float*)(ws + 20480);        // 4544 floats
  float* x    = (float*)(ws + 65536);        // 4096*32 f32
  float* x1 = x  + BROWS*32;
  float* x2 = x1 + BROWS*32;
  float* x3 = x2 + BROWS*32;                 // ends ~2.2 MB into ws

  hipMemsetAsync(ws, 0, 20480, stream);      // zero flag + sharded stats
  k_detect<<<1, 64, 0, stream>>>((const u16*)u, flag);
  k_stats_u<<<512, 256, 0, stream>>>(u, S, flag);
  k_foldL1<<<1, 64, 0, stream>>>(S, FW, pg1,pb1,pw1, og1,ob1,ow1, flag);
  k_pass1<<<2048, 256, 0, stream>>>(u, pg1,pb1,pw1, og1,ob1,ow1, S, flag);
  k_foldL<<<1, 64, 0, stream>>>(S, S_O1, S_A1, FW, FW2P, C2P, FW2O, C2O,
                                pg2,pb2,pw2, og2,ob2,ow2, flag);
  k_pass2<<<2048, 256, 0, stream>>>(u, FW, S, flag);
  k_foldL<<<1, 64, 0, stream>>>(S, S_O12, S_A2, FW, FW3P, C3P, FW3O, C3O,
                                pg3,pb3,pw3, og3,ob3,ow3, flag);
  k_pass3<<<2048, 256, 0, stream>>>(u, mask, FW, x, S, flag);
  k_theta<<<16, 256, 0, stream>>>(x,  S, S_X,  tg1,tb1,tw1, x1, S_X1, flag);
  k_theta<<<16, 256, 0, stream>>>(x1, S, S_X1, tg2,tb2,tw2, x2, S_X2, flag);
  k_theta<<<16, 256, 0, stream>>>(x2, S, S_X2, tg3,tb3,tw3, x3, S_X3, flag);
  k_theta4<<<16, 256, 0, stream>>>(x3, S, S_X3, tg4,tb4,tw4,tbb4, d_out, flag);
}

// Round 6
// 504.258 us; speedup vs baseline: 1.0338x; 1.0338x over previous
//
#include <hip/hip_runtime.h>

typedef unsigned int u32;
typedef unsigned short u16;

#define ROWS  524288   // B*N
#define BROWS 4096     // B
#define EPS   1e-5f

// ---- stats: 4 shards of 1024 floats each; consumers sum shards ----
#define S_U   0     // 4 sum + 4 ssq
#define S_O1  8     // 32 sum + 32 ssq
#define S_A1  72
#define S_O12 136
#define S_A2  200
#define S_X   264
#define S_X1  328
#define S_X2  392
#define S_X3  456
#define SHARD 1024  // floats

// ---- folded-weight block FW (float offsets) ----
#define FW1P 0
#define C1P  128
#define FW1O 160
#define C1O  288
#define FW2P 320
#define C2P  1344
#define FW2O 1376
#define C2O  2400
#define FW3P 2432
#define C3P  3456
#define FW3O 3488
#define C3O  4512

__device__ __forceinline__ float bl(u32 u){ return __uint_as_float(u << 16); }
__device__ __forceinline__ float bh(u32 u){ return __uint_as_float(u & 0xFFFF0000u); }
__device__ __forceinline__ float b2f(u16 h){ return __uint_as_float(((u32)h) << 16); }
__device__ __forceinline__ u16 f2b(float f){
  u32 u = __float_as_uint(f);
  return (u16)((u + 0x7FFFu + ((u >> 16) & 1u)) >> 16);   // RNE
}
__device__ __forceinline__ float tanh_fast(float x){
  float e = __expf(2.0f * x);
  return 1.0f - 2.0f * __builtin_amdgcn_rcpf(e + 1.0f);
}
__device__ __forceinline__ float sumsh(const float* __restrict__ S, int off){
  return S[off] + S[SHARD+off] + S[2*SHARD+off] + S[3*SHARD+off];
}

template<bool F32>
__device__ __forceinline__ float rdp(const void* p, int i){
  if (F32) return ((const float*)p)[i];
  return b2f(((const u16*)p)[i]);
}
template<bool F32>
__device__ __forceinline__ void load_u4(const void* u, int r, float* f){
  if (F32){
    float4 v = ((const float4*)u)[r];
    f[0]=v.x; f[1]=v.y; f[2]=v.z; f[3]=v.w;
  } else {
    uint2 v = ((const uint2*)u)[r];
    f[0]=bl(v.x); f[1]=bh(v.x); f[2]=bl(v.y); f[3]=bh(v.y);
  }
}

// ---------------- dtype detection ----------------
__global__ void k_detect(const u16* __restrict__ u, int* __restrict__ flag){
  int t = threadIdx.x;   // 64
  int bad = 0;
  for (int i = t*4; i < t*4+4; ++i){
    int e = (u[i] >> 7) & 0xFF;
    bad += (e >= 0x90) ? 1 : 0;
  }
#pragma unroll
  for (int off = 32; off >= 1; off >>= 1) bad += __shfl_down(bad, off);
  if (t == 0) *flag = (bad >= 4) ? 1 : 0;
}

// ---------------- stats of u (4 cols) ----------------
template<bool F32>
__device__ __forceinline__ void stats_u_body(const void* __restrict__ u, float* __restrict__ S){
  int tid = blockIdx.x*blockDim.x + threadIdx.x;
  int nt  = gridDim.x*blockDim.x;
  float s[4]={0,0,0,0}, q[4]={0,0,0,0};
  for (int r = tid; r < ROWS; r += nt){
    float f[4]; load_u4<F32>(u, r, f);
#pragma unroll
    for (int k=0;k<4;++k){ s[k]+=f[k]; q[k]+=f[k]*f[k]; }
  }
#pragma unroll
  for (int off=32; off>=1; off>>=1){
#pragma unroll
    for (int k=0;k<4;++k){ s[k]+=__shfl_down(s[k],off); q[k]+=__shfl_down(q[k],off); }
  }
  if ((threadIdx.x & 63) == 0){
    float* Sh = S + (blockIdx.x & 3)*SHARD;
#pragma unroll
    for (int k=0;k<4;++k){ atomicAdd(&Sh[S_U+k], s[k]); atomicAdd(&Sh[S_U+4+k], q[k]); }
  }
}
__global__ __launch_bounds__(256) void k_stats_u(const void* __restrict__ u, float* __restrict__ S,
                                                 const int* __restrict__ flag){
  if (*flag) stats_u_body<true>(u,S); else stats_u_body<false>(u,S);
}

// ---------------- pass1: stats of o1, a1 (lane owns column) ----------------
template<bool F32>
__device__ __forceinline__ void pass1_body(
    const void* __restrict__ u,
    const void* pg1, const void* pb1, const void* pw1,
    const void* og1, const void* ob1, const void* ow1,
    float* __restrict__ S, float* lds)
{
  int tid = blockIdx.x*blockDim.x + threadIdx.x;
  int j = tid & 31;
  int g = tid >> 5;
  int ng = (gridDim.x*blockDim.x) >> 5;
  float wp[4], wo[4], cp=0.f, co=0.f;
#pragma unroll
  for (int k=0;k<4;++k){
    float m    = sumsh(S, S_U+k)   * (1.0f/ROWS);
    float var  = sumsh(S, S_U+4+k) * (1.0f/ROWS) - m*m;
    float rstd = rsqrtf(var + EPS);
    float sp = rdp<F32>(pg1,k)*rstd, so = rdp<F32>(og1,k)*rstd;
    float Wp = rdp<F32>(pw1, j*4+k), Wo = rdp<F32>(ow1, j*4+k);
    wp[k]=Wp*sp; wo[k]=Wo*so;
    cp += Wp*(rdp<F32>(pb1,k)-m*sp);
    co += Wo*(rdp<F32>(ob1,k)-m*so);
  }
  float so1=0,qo1=0,sa1=0,qa1=0;
  for (int r=g; r<ROWS; r+=ng){
    float f[4]; load_u4<F32>(u,r,f);
    float vp = cp + wp[0]*f[0]+wp[1]*f[1]+wp[2]*f[2]+wp[3]*f[3];
    float vo = co + wo[0]*f[0]+wo[1]*f[1]+wo[2]*f[2]+wo[3]*f[3];
    float tp = tanh_fast(vp), to = tanh_fast(vo);
    so1+=tp; qo1+=tp*tp; sa1+=to; qa1+=to*to;
  }
  so1+=__shfl_down(so1,32); qo1+=__shfl_down(qo1,32);
  sa1+=__shfl_down(sa1,32); qa1+=__shfl_down(qa1,32);
  int wv = threadIdx.x>>6, ln = threadIdx.x&63;
  if (ln<32){ float* p = lds + (wv*32+ln)*4; p[0]=so1; p[1]=qo1; p[2]=sa1; p[3]=qa1; }
  __syncthreads();
  if (threadIdx.x < 32){
    float a=0,b=0,c=0,d=0;
#pragma unroll
    for (int w=0;w<4;++w){ const float* p = lds + (w*32+threadIdx.x)*4; a+=p[0]; b+=p[1]; c+=p[2]; d+=p[3]; }
    float* Sh = S + (blockIdx.x & 3)*SHARD;
    atomicAdd(&Sh[S_O1+threadIdx.x], a); atomicAdd(&Sh[S_O1+32+threadIdx.x], b);
    atomicAdd(&Sh[S_A1+threadIdx.x], c); atomicAdd(&Sh[S_A1+32+threadIdx.x], d);
  }
}
__global__ __launch_bounds__(256) void k_pass1(
    const void* u, const void* pg1, const void* pb1, const void* pw1,
    const void* og1, const void* ob1, const void* ow1,
    float* S, const int* __restrict__ flag)
{
  __shared__ float lds[4*32*4];
  if (*flag) pass1_body<true>(u,pg1,pb1,pw1,og1,ob1,ow1,S,lds);
  else       pass1_body<false>(u,pg1,pb1,pw1,og1,ob1,ow1,S,lds);
}

// ---------------- BN+Linear fold ----------------
template<bool F32, int KDIM>
__device__ __forceinline__ void fold_one(const float* __restrict__ S, int off, float invN,
    const void* g, const void* b, const void* W,
    float* __restrict__ Wf, float* __restrict__ cf, int j)
{
  float c = 0.f;
#pragma unroll
  for (int k=0;k<KDIM;++k){
    float m    = sumsh(S, off+k)*invN;
    float var  = sumsh(S, off+KDIM+k)*invN - m*m;
    float rstd = rsqrtf(var+EPS);
    float s  = rdp<F32>(g,k)*rstd;
    float Wv = rdp<F32>(W, j*KDIM+k);
    Wf[k*32+j] = Wv*s;
    c += Wv*(rdp<F32>(b,k)-m*s);
  }
  cf[j] = c;
}

__global__ void k_foldL1(const float* __restrict__ S, float* __restrict__ FW,
    const void* pg1, const void* pb1, const void* pw1,
    const void* og1, const void* ob1, const void* ow1,
    const int* __restrict__ flag)
{
  int t = threadIdx.x;   // 64
  int j = t & 31;
  int isf = *flag;
  if (t < 32){
    if (isf) fold_one<true ,4>(S, S_U, 1.0f/ROWS, pg1,pb1,pw1, FW+FW1P, FW+C1P, j);
    else     fold_one<false,4>(S, S_U, 1.0f/ROWS, pg1,pb1,pw1, FW+FW1P, FW+C1P, j);
  } else {
    if (isf) fold_one<true ,4>(S, S_U, 1.0f/ROWS, og1,ob1,ow1, FW+FW1O, FW+C1O, j);
    else     fold_one<false,4>(S, S_U, 1.0f/ROWS, og1,ob1,ow1, FW+FW1O, FW+C1O, j);
  }
}

__global__ void k_foldL(const float* __restrict__ S, int offA, int offB, float* __restrict__ FW,
    int offWp, int offCp, int offWo, int offCo,
    const void* gp, const void* bp, const void* Wp,
    const void* go, const void* bo, const void* Wo,
    const int* __restrict__ flag)
{
  int t = threadIdx.x;   // 64
  int j = t & 31;
  int isf = *flag;
  if (t < 32){
    if (isf) fold_one<true ,32>(S, offA, 1.0f/ROWS, gp,bp,Wp, FW+offWp, FW+offCp, j);
    else     fold_one<false,32>(S, offA, 1.0f/ROWS, gp,bp,Wp, FW+offWp, FW+offCp, j);
  } else {
    if (isf) fold_one<true ,32>(S, offB, 1.0f/ROWS, go,bo,Wo, FW+offWo, FW+offCo, j);
    else     fold_one<false,32>(S, offB, 1.0f/ROWS, go,bo,Wo, FW+offWo, FW+offCo, j);
  }
}

// ================= x-in-LDS chain engine =================
// Registers hold ONLY acc[32]+f[4] (~45 live); the matvec input vector lives in the
// thread's private 33-float LDS slot (bank (tid+j)%32 -> 2-way for wave64 = free).
// Folded weights are wave-uniform -> SGPR operands in v_fmac. This fits the ~60-VGPR
// allocation the compiler insists on (R2-R5), eliminating spills structurally.

// o1/a1 from f[4]; result written to slot X
template<bool PHI>
__device__ __forceinline__ void chainL1(const float* f, const float* __restrict__ FW, float* X){
  const int F1 = PHI?FW1P:FW1O, C1 = PHI?C1P:C1O;
  float acc[32];
#pragma unroll
  for (int j=0;j<32;++j)
    acc[j] = tanh_fast(FW[C1+j] + f[0]*FW[F1+j] + f[1]*FW[F1+32+j] + f[2]*FW[F1+64+j] + f[3]*FW[F1+96+j]);
#pragma unroll
  for (int j=0;j<32;++j) X[j] = acc[j];
}

// 32x32 matvec from slot X into acc (init with bias at FW[CB+j])
__device__ __forceinline__ void matvec32(const float* __restrict__ FW, int WB, int CB,
                                         const float* X, float* acc){
#pragma unroll
  for (int j=0;j<32;++j) acc[j] = FW[CB+j];
#pragma unroll
  for (int k=0;k<32;++k){
    float xk = X[k];
#pragma unroll
    for (int j=0;j<32;++j) acc[j] = fmaf(FW[WB+k*32+j], xk, acc[j]);
  }
}

// ---------------- pass2 (merged): stats of o12 AND a2 ----------------
__device__ __forceinline__ void reduce_from_lds(const float* lds, float* lds2,
                                                float* __restrict__ S, int offS, int shard)
{
  int tid = threadIdx.x;
  __syncthreads();
  {
    int j = tid & 31, seg = tid >> 5;
    float s=0.f, q=0.f;
    for (int q2=0;q2<32;++q2){
      float v = lds[(seg*32+q2)*33 + j];
      s += v; q = fmaf(v,v,q);
    }
    lds2[seg*32+j] = s;
    lds2[256 + seg*32+j] = q;
  }
  __syncthreads();
  if (tid < 64){
    int j = tid & 31; bool isq = tid >= 32;
    const float* src = lds2 + (isq?256:0);
    float tot=0.f;
#pragma unroll
    for (int sg=0;sg<8;++sg) tot += src[sg*32+j];
    atomicAdd(&S[shard*SHARD + offS + (isq?32:0) + j], tot);
  }
  __syncthreads();
}

template<bool F32>
__device__ __forceinline__ void pass2_body(const void* __restrict__ u,
    const float* __restrict__ FW, float* __restrict__ S, float* Xs, float* lds2)
{
  int tid = threadIdx.x;
  int r = blockIdx.x*256 + tid;
  int shard = blockIdx.x & 3;
  float f[4]; load_u4<F32>(u,r,f);
  float* X = Xs + tid*33;
  float acc[32];
  // phi: o1 -> o12
  chainL1<true>(f, FW, X);
  matvec32(FW, FW2P, C2P, X, acc);
#pragma unroll
  for (int j=0;j<32;++j) X[j] = X[j] + tanh_fast(acc[j]);   // o12
  reduce_from_lds(Xs, lds2, S, S_O12, shard);
  // omega: a1 -> a2
  chainL1<false>(f, FW, X);
  matvec32(FW, FW2O, C2O, X, acc);
#pragma unroll
  for (int j=0;j<32;++j) X[j] = tanh_fast(acc[j]);          // a2
  reduce_from_lds(Xs, lds2, S, S_A2, shard);
}
__global__ __launch_bounds__(256) void k_pass2(const void* __restrict__ u, const float* __restrict__ FW,
                                               float* __restrict__ S, const int* __restrict__ flag){
  __shared__ float Xs[256*33];
  __shared__ float lds2[512];
  if (*flag) pass2_body<true >(u,FW,S,Xs,lds2);
  else       pass2_body<false>(u,FW,S,Xs,lds2);
}

// ---------------- pass3: omega->at(bf16 LDS), phi->xm, pool; fused stats of x ----------------
template<bool F32>
__device__ __forceinline__ void pass3_body(const void* __restrict__ u, const int* __restrict__ mask,
    const float* __restrict__ FW, float* __restrict__ x, float* __restrict__ S,
    float* Xs, u16* at16, float* red2)
{
  int n = threadIdx.x;                 // 256: two 128-neighbor groups
  int r = blockIdx.x*256 + n;
  float f[4]; load_u4<F32>(u,r,f);
  float* X  = Xs + n*33;
  u16*   AT = at16 + n*34;
  float acc[32];

  // ---- omega: a1 -> a2 -> logits -> softmax -> at (bf16, own LDS slot) ----
  chainL1<false>(f, FW, X);
  matvec32(FW, FW2O, C2O, X, acc);
#pragma unroll
  for (int j=0;j<32;++j) X[j] = tanh_fast(acc[j]);          // a2
  matvec32(FW, FW3O, C3O, X, acc);                          // logits in acc
  float mx = acc[0];
#pragma unroll
  for (int j=1;j<32;++j) mx = fmaxf(mx, acc[j]);
  float sum = 0.f;
#pragma unroll
  for (int j=0;j<32;++j){ float e = __expf(acc[j]-mx); acc[j]=e; sum+=e; }
  float inv = __builtin_amdgcn_rcpf(sum);
  bool mz = (mask[r] == 0);
#pragma unroll
  for (int j=0;j<32;++j){
    float at = acc[j]*inv;
    if (mz) at = -__builtin_inff();
    AT[j] = f2b(at);
  }

  // ---- phi: o1 -> o12 -> xm, multiply by at ----
  chainL1<true>(f, FW, X);
  matvec32(FW, FW2P, C2P, X, acc);
#pragma unroll
  for (int j=0;j<32;++j) X[j] = X[j] + tanh_fast(acc[j]);   // o12
  matvec32(FW, FW3P, C3P, X, acc);
#pragma unroll
  for (int j=0;j<32;++j) X[j] = (X[j] + tanh_fast(acc[j])) * b2f(AT[j]);   // xm*at
  __syncthreads();

  // pool over 128 neighbors (2 groups per block)
  {
    int jj = n & 31, c = (n >> 5) & 3, half = n >> 7;
    float s2 = 0.f;
    for (int q2=0;q2<32;++q2) s2 += Xs[(half*128 + c*32 + q2)*33 + jj];
    red2[n] = s2;
  }
  __syncthreads();
  if (n < 64){
    int half = n >> 5, j = n & 31;
    float v = red2[half*128+j] + red2[half*128+32+j] + red2[half*128+64+j] + red2[half*128+96+j];
    x[(blockIdx.x*2 + half)*32 + j] = v;
    float* Sh = S + (blockIdx.x & 3)*SHARD;
    atomicAdd(&Sh[S_X+j], v);          // fused stats of x
    atomicAdd(&Sh[S_X+32+j], v*v);
  }
}
__global__ __launch_bounds__(256) void k_pass3(const void* __restrict__ u, const int* __restrict__ mask,
    const float* __restrict__ FW, float* __restrict__ x, float* __restrict__ S,
    const int* __restrict__ flag){
  __shared__ float Xs[256*33];     // 33.8 KB
  __shared__ u16   at16[256*34];   // 17.4 KB
  __shared__ float red2[256];
  if (*flag) pass3_body<true >(u,mask,FW,x,S,Xs,at16,red2);
  else       pass3_body<false>(u,mask,FW,x,S,Xs,at16,red2);
}

// ---------------- block-wide column reduce (blockDim==256) ----------------
__device__ __forceinline__ void block_reduce32(const float* vals, float* lds, float* __restrict__ dst){
  int t = threadIdx.x;
#pragma unroll
  for (int j=0;j<32;++j) lds[t*33+j] = vals[j];
  __syncthreads();
  if (t < 32){
    float tot=0.f;
    for (int q2=0;q2<256;++q2) tot += lds[q2*33+t];
    atomicAdd(&dst[t], tot);
  }
  __syncthreads();
}

// ---------------- theta layer ----------------
template<bool F32>
__device__ __forceinline__ void theta_body(const float* __restrict__ X, float* __restrict__ S, int offin,
    const void* g, const void* bt, const void* W, float* __restrict__ Y, int offout, float* lds)
{
  int r = blockIdx.x*blockDim.x + threadIdx.x;   // 4096 rows exactly
  int tid = threadIdx.x;
  float* Xp = lds + tid*33;
#pragma unroll
  for (int k=0;k<32;++k){
    float m    = sumsh(S, offin+k)    * (1.0f/BROWS);
    float var  = sumsh(S, offin+32+k) * (1.0f/BROWS) - m*m;
    float rstd = rsqrtf(var + EPS);
    Xp[k] = (X[(size_t)r*32+k] - m) * (rdp<F32>(g,k)*rstd) + rdp<F32>(bt,k);
  }
  float out[32];
#pragma unroll
  for (int j=0;j<32;++j){
    float acc = 0.f;
#pragma unroll
    for (int k=0;k<32;++k) acc = fmaf(rdp<F32>(W, j*32+k), Xp[k], acc);
    out[j] = tanh_fast(acc);
    Y[(size_t)r*32+j] = out[j];
  }
  __syncthreads();
  float* Sh = S + (blockIdx.x & 3)*SHARD;
  block_reduce32(out, lds, Sh+offout);
#pragma unroll
  for (int j=0;j<32;++j) out[j] *= out[j];
  block_reduce32(out, lds, Sh+offout+32);
}
__global__ __launch_bounds__(256) void k_theta(const float* X, float* S, int offin,
    const void* g, const void* bt, const void* W, float* Y, int offout, const int* __restrict__ flag){
  __shared__ float lds[256*33];
  if (*flag) theta_body<true >(X,S,offin,g,bt,W,Y,offout,lds);
  else       theta_body<false>(X,S,offin,g,bt,W,Y,offout,lds);
}

// ---------------- final layer ----------------
template<bool F32>
__device__ __forceinline__ void theta4_body(const float* __restrict__ X, const float* __restrict__ S, int offin,
    const void* g, const void* bt, const void* w4, const void* b4, void* out)
{
  int r = blockIdx.x*blockDim.x + threadIdx.x;
  float acc = rdp<F32>(b4, 0);
#pragma unroll
  for (int k=0;k<32;++k){
    float m    = sumsh(S, offin+k)    * (1.0f/BROWS);
    float var  = sumsh(S, offin+32+k) * (1.0f/BROWS) - m*m;
    float rstd = rsqrtf(var + EPS);
    float xn = (X[(size_t)r*32+k] - m) * (rdp<F32>(g,k)*rstd) + rdp<F32>(bt,k);
    acc = fmaf(rdp<F32>(w4,k), xn, acc);
  }
  if (F32) ((float*)out)[r] = acc;
  else     ((u16*)out)[r]  = f2b(acc);
}
__global__ __launch_bounds__(256) void k_theta4(const float* X, const float* S, int offin,
    const void* g, const void* bt, const void* w4, const void* b4, void* out, const int* __restrict__ flag){
  if (*flag) theta4_body<true >(X,S,offin,g,bt,w4,b4,out);
  else       theta4_body<false>(X,S,offin,g,bt,w4,b4,out);
}

extern "C" void kernel_launch(void* const* d_in, const int* in_sizes, int n_in,
                              void* d_out, int out_size, void* d_ws, size_t ws_size,
                              hipStream_t stream)
{
  const void* u    = d_in[0];
  const int*  mask = (const int*)d_in[1];
  const void *pg1=d_in[2],  *pb1=d_in[3],  *pw1=d_in[4];
  const void *pg2=d_in[5],  *pb2=d_in[6],  *pw2=d_in[7];
  const void *pg3=d_in[8],  *pb3=d_in[9],  *pw3=d_in[10];
  const void *og1=d_in[11], *ob1=d_in[12], *ow1=d_in[13];
  const void *og2=d_in[14], *ob2=d_in[15], *ow2=d_in[16];
  const void *og3=d_in[17], *ob3=d_in[18], *ow3=d_in[19];
  const void *tg1=d_in[20], *tb1=d_in[21], *tw1=d_in[22];
  const void *tg2=d_in[23], *tb2=d_in[24], *tw2=d_in[25];
  const void *tg3=d_in[26], *tb3=d_in[27], *tw3=d_in[28];
  const void *tg4=d_in[29], *tb4=d_in[30], *tw4=d_in[31], *tbb4=d_in[32];

  char* ws = (char*)d_ws;
  int*   flag = (int*)ws;                    // byte 0
  float* S    = (float*)(ws + 1024);         // 4 shards x 1024 floats = 16 KB
  float* FW   = (float*)(ws + 20480);        // 4544 floats
  float* x    = (float*)(ws + 65536);        // 4096*32 f32
  float* x1 = x  + BROWS*32;
  float* x2 = x1 + BROWS*32;
  float* x3 = x2 + BROWS*32;                 // ends ~2.2 MB into ws

  hipMemsetAsync(ws, 0, 20480, stream);      // zero flag + sharded stats
  k_detect<<<1, 64, 0, stream>>>((const u16*)u, flag);
  k_stats_u<<<512, 256, 0, stream>>>(u, S, flag);
  k_foldL1<<<1, 64, 0, stream>>>(S, FW, pg1,pb1,pw1, og1,ob1,ow1, flag);
  k_pass1<<<2048, 256, 0, stream>>>(u, pg1,pb1,pw1, og1,ob1,ow1, S, flag);
  k_foldL<<<1, 64, 0, stream>>>(S, S_O1, S_A1, FW, FW2P, C2P, FW2O, C2O,
                                pg2,pb2,pw2, og2,ob2,ow2, flag);
  k_pass2<<<2048, 256, 0, stream>>>(u, FW, S, flag);
  k_foldL<<<1, 64, 0, stream>>>(S, S_O12, S_A2, FW, FW3P, C3P, FW3O, C3O,
                                pg3,pb3,pw3, og3,ob3,ow3, flag);
  k_pass3<<<2048, 256, 0, stream>>>(u, mask, FW, x, S, flag);
  k_theta<<<16, 256, 0, stream>>>(x,  S, S_X,  tg1,tb1,tw1, x1, S_X1, flag);
  k_theta<<<16, 256, 0, stream>>>(x1, S, S_X1, tg2,tb2,tw2, x2, S_X2, flag);
  k_theta<<<16, 256, 0, stream>>>(x2, S, S_X2, tg3,tb3,tw3, x3, S_X3, flag);
  k_theta4<<<16, 256, 0, stream>>>(x3, S, S_X3, tg4,tb4,tw4,tbb4, d_out, flag);
}

// Round 9
// 460.387 us; speedup vs baseline: 1.1323x; 1.0953x over previous
//
#include <hip/hip_runtime.h>

typedef unsigned int u32;
typedef unsigned short u16;
typedef __attribute__((ext_vector_type(8))) _Float16 half8;
typedef __attribute__((ext_vector_type(4))) float f32x4;

#define ROWS  524288   // B*N
#define BROWS 4096     // B
#define EPS   1e-5f

// ---- stats: 4 shards of 1024 floats each; consumers sum shards ----
#define S_U   0
#define S_O1  8
#define S_A1  72
#define S_O12 136
#define S_A2  200
#define S_X   264
#define S_X1  328
#define S_X2  392
#define S_X3  456
#define SHARD 1024

// ---- folded-weight block FW (float offsets) ----
#define FW1P 0
#define C1P  128
#define FW1O 160
#define C1O  288
#define FW2P 320
#define C2P  1344
#define FW2O 1376
#define C2O  2400
#define FW3P 2432
#define C3P  3456
#define FW3O 3488
#define C3O  4512

#define XSTR 40   // LDS row stride in u16: 80 B -> 16-B aligned b128, 2-way banks (free)

__device__ __forceinline__ float bl(u32 u){ return __uint_as_float(u << 16); }
__device__ __forceinline__ float bh(u32 u){ return __uint_as_float(u & 0xFFFF0000u); }
__device__ __forceinline__ float b2f(u16 h){ return __uint_as_float(((u32)h) << 16); }
__device__ __forceinline__ u16 f2b(float f){
  u32 u = __float_as_uint(f);
  return (u16)((u + 0x7FFFu + ((u >> 16) & 1u)) >> 16);   // RNE (bf16, output only)
}
// f16 helpers: single-op native converts
__device__ __forceinline__ u16 f2h(float f){ _Float16 h = (_Float16)f; return __builtin_bit_cast(u16, h); }
__device__ __forceinline__ float h2f(u16 x){ return (float)__builtin_bit_cast(_Float16, x); }
__device__ __forceinline__ u32 pack2h(float a, float b){     // v_cvt_pkrtz_f16_f32, 1 op
  auto v = __builtin_amdgcn_cvt_pkrtz(a, b);                 // __fp16 ext_vector(2)
  return __builtin_bit_cast(u32, v);
}
__device__ __forceinline__ float lo16(u32 w){ return h2f((u16)(w & 0xFFFF)); }
__device__ __forceinline__ float hi16(u32 w){ return h2f((u16)(w >> 16)); }

__device__ __forceinline__ float tanh_fast(float x){
  float e = __expf(2.0f * x);
  return 1.0f - 2.0f * __builtin_amdgcn_rcpf(e + 1.0f);
}
__device__ __forceinline__ float sumsh(const float* __restrict__ S, int off){
  return S[off] + S[SHARD+off] + S[2*SHARD+off] + S[3*SHARD+off];
}

template<bool F32>
__device__ __forceinline__ float rdp(const void* p, int i){
  if (F32) return ((const float*)p)[i];
  return b2f(((const u16*)p)[i]);
}
template<bool F32>
__device__ __forceinline__ void load_u4(const void* u, int r, float* f){
  if (F32){
    float4 v = ((const float4*)u)[r];
    f[0]=v.x; f[1]=v.y; f[2]=v.z; f[3]=v.w;
  } else {
    uint2 v = ((const uint2*)u)[r];
    f[0]=bl(v.x); f[1]=bh(v.x); f[2]=bl(v.y); f[3]=bh(v.y);
  }
}

// ---------------- dtype detection ----------------
__global__ void k_detect(const u16* __restrict__ u, int* __restrict__ flag){
  int t = threadIdx.x;   // 64
  int bad = 0;
  for (int i = t*4; i < t*4+4; ++i){
    int e = (u[i] >> 7) & 0xFF;
    bad += (e >= 0x90) ? 1 : 0;
  }
#pragma unroll
  for (int off = 32; off >= 1; off >>= 1) bad += __shfl_down(bad, off);
  if (t == 0) *flag = (bad >= 4) ? 1 : 0;
}

// ---------------- stats of u (4 cols) ----------------
template<bool F32>
__device__ __forceinline__ void stats_u_body(const void* __restrict__ u, float* __restrict__ S){
  int tid = blockIdx.x*blockDim.x + threadIdx.x;
  int nt  = gridDim.x*blockDim.x;
  float s[4]={0,0,0,0}, q[4]={0,0,0,0};
  for (int r = tid; r < ROWS; r += nt){
    float f[4]; load_u4<F32>(u, r, f);
#pragma unroll
    for (int k=0;k<4;++k){ s[k]+=f[k]; q[k]+=f[k]*f[k]; }
  }
#pragma unroll
  for (int off=32; off>=1; off>>=1){
#pragma unroll
    for (int k=0;k<4;++k){ s[k]+=__shfl_down(s[k],off); q[k]+=__shfl_down(q[k],off); }
  }
  if ((threadIdx.x & 63) == 0){
    float* Sh = S + (blockIdx.x & 3)*SHARD;
#pragma unroll
    for (int k=0;k<4;++k){ atomicAdd(&Sh[S_U+k], s[k]); atomicAdd(&Sh[S_U+4+k], q[k]); }
  }
}
__global__ __launch_bounds__(256) void k_stats_u(const void* __restrict__ u, float* __restrict__ S,
                                                 const int* __restrict__ flag){
  if (*flag) stats_u_body<true>(u,S); else stats_u_body<false>(u,S);
}

// ---------------- BN+Linear fold ----------------
template<bool F32, int KDIM>
__device__ __forceinline__ void fold_one(const float* __restrict__ S, int off, float invN,
    const void* g, const void* b, const void* W,
    float* __restrict__ Wf, float* __restrict__ cf, int j)
{
  float c = 0.f;
#pragma unroll
  for (int k=0;k<KDIM;++k){
    float m    = sumsh(S, off+k)*invN;
    float var  = sumsh(S, off+KDIM+k)*invN - m*m;
    float rstd = rsqrtf(var+EPS);
    float s  = rdp<F32>(g,k)*rstd;
    float Wv = rdp<F32>(W, j*KDIM+k);
    Wf[k*32+j] = Wv*s;
    c += Wv*(rdp<F32>(b,k)-m*s);
  }
  cf[j] = c;
}

__global__ void k_foldL1(const float* __restrict__ S, float* __restrict__ FW,
    const void* pg1, const void* pb1, const void* pw1,
    const void* og1, const void* ob1, const void* ow1,
    const int* __restrict__ flag)
{
  int t = threadIdx.x;   // 64
  int j = t & 31;
  int isf = *flag;
  if (t < 32){
    if (isf) fold_one<true ,4>(S, S_U, 1.0f/ROWS, pg1,pb1,pw1, FW+FW1P, FW+C1P, j);
    else     fold_one<false,4>(S, S_U, 1.0f/ROWS, pg1,pb1,pw1, FW+FW1P, FW+C1P, j);
  } else {
    if (isf) fold_one<true ,4>(S, S_U, 1.0f/ROWS, og1,ob1,ow1, FW+FW1O, FW+C1O, j);
    else     fold_one<false,4>(S, S_U, 1.0f/ROWS, og1,ob1,ow1, FW+FW1O, FW+C1O, j);
  }
}

__global__ void k_foldL(const float* __restrict__ S, int offA, int offB, float* __restrict__ FW,
    int offWp, int offCp, int offWo, int offCo,
    const void* gp, const void* bp, const void* Wp,
    const void* go, const void* bo, const void* Wo,
    const int* __restrict__ flag)
{
  int t = threadIdx.x;   // 64
  int j = t & 31;
  int isf = *flag;
  if (t < 32){
    if (isf) fold_one<true ,32>(S, offA, 1.0f/ROWS, gp,bp,Wp, FW+offWp, FW+offCp, j);
    else     fold_one<false,32>(S, offA, 1.0f/ROWS, gp,bp,Wp, FW+offWp, FW+offCp, j);
  } else {
    if (isf) fold_one<true ,32>(S, offB, 1.0f/ROWS, go,bo,Wo, FW+offWo, FW+offCo, j);
    else     fold_one<false,32>(S, offB, 1.0f/ROWS, go,bo,Wo, FW+offWo, FW+offCo, j);
  }
}

// ================= f16 MFMA building blocks =================

// L1 chain (K=4 affine + tanh) -> thread's own X row as f16 (pkrtz pairs).
template<bool PHI>
__device__ __forceinline__ void chain1_to_lds(const float* f, const float* __restrict__ FW, u16* Xrow){
  const int F1 = PHI?FW1P:FW1O, C1 = PHI?C1P:C1O;
  u32 buf[16];
#pragma unroll
  for (int jp=0; jp<16; ++jp){
    int j0 = 2*jp, j1 = 2*jp+1;
    float a0 = tanh_fast(FW[C1+j0] + f[0]*FW[F1+j0] + f[1]*FW[F1+32+j0] + f[2]*FW[F1+64+j0] + f[3]*FW[F1+96+j0]);
    float a1 = tanh_fast(FW[C1+j1] + f[0]*FW[F1+j1] + f[1]*FW[F1+32+j1] + f[2]*FW[F1+64+j1] + f[3]*FW[F1+96+j1]);
    buf[jp] = pack2h(a0, a1);
  }
#pragma unroll
  for (int c=0;c<4;++c){
    uint4 v; v.x = buf[c*4]; v.y = buf[c*4+1]; v.z = buf[c*4+2]; v.w = buf[c*4+3];
    *(uint4*)&Xrow[c*8] = v;
  }
}

// One 32x32 layer via mfma_f32_16x16x32_f16, X updated in place (wave-local rows).
#define KIND_TANH       0
#define KIND_NONE       1
#define KIND_TANHRES    2
#define KIND_TANHRES_AT 3
template<int KIND>
__device__ __forceinline__ void mfma_layer(u16* X, const u16* Wt, const float* Cb,
                                           int L, int wv, int lane, const u16* AT)
{
  int ln15 = lane & 15, quad = lane >> 4;
  half8 b0 = *(const half8*)&Wt[(L*32 + ln15     )*XSTR + quad*8];
  half8 b1 = *(const half8*)&Wt[(L*32 + ln15 + 16)*XSTR + quad*8];
  float bias0 = Cb[L*32 + ln15], bias1 = Cb[L*32 + ln15 + 16];
  int rowbase = wv*64;
#pragma unroll
  for (int Mt=0; Mt<4; ++Mt){
    int rb = rowbase + Mt*16;
    half8 a = *(const half8*)&X[(rb + ln15)*XSTR + quad*8];
    f32x4 c0 = {0.f,0.f,0.f,0.f}, c1 = {0.f,0.f,0.f,0.f};
    c0 = __builtin_amdgcn_mfma_f32_16x16x32_f16(a, b0, c0, 0,0,0);
    c1 = __builtin_amdgcn_mfma_f32_16x16x32_f16(a, b1, c1, 0,0,0);
#pragma unroll
    for (int reg=0; reg<4; ++reg){
      int r = rb + quad*4 + reg;
      float v0 = c0[reg] + bias0;
      float v1 = c1[reg] + bias1;
      if (KIND == KIND_TANH){ v0 = tanh_fast(v0); v1 = tanh_fast(v1); }
      else if (KIND == KIND_TANHRES){
        v0 = h2f(X[r*XSTR + ln15     ]) + tanh_fast(v0);
        v1 = h2f(X[r*XSTR + ln15 + 16]) + tanh_fast(v1);
      } else if (KIND == KIND_TANHRES_AT){
        v0 = (h2f(X[r*XSTR + ln15     ]) + tanh_fast(v0)) * h2f(AT[r*XSTR + ln15     ]);
        v1 = (h2f(X[r*XSTR + ln15 + 16]) + tanh_fast(v1)) * h2f(AT[r*XSTR + ln15 + 16]);
      }
      X[r*XSTR + ln15     ] = f2h(v0);
      X[r*XSTR + ln15 + 16] = f2h(v1);
    }
  }
}

// Column stats (sum, sumsq) of the 256x32 f16 X tile -> sharded atomics.
__device__ __forceinline__ void reduce_f16(const u16* X, float* lds2,
                                           float* __restrict__ S, int offS, int shard)
{
  int tid = threadIdx.x;
  __syncthreads();
  {
    int j = tid & 31, seg = tid >> 5;
    float s=0.f, q=0.f;
    for (int q2=0;q2<32;++q2){
      float v = h2f(X[(seg*32+q2)*XSTR + j]);
      s += v; q = fmaf(v,v,q);
    }
    lds2[seg*32+j] = s;
    lds2[256 + seg*32+j] = q;
  }
  __syncthreads();
  if (tid < 64){
    int j = tid & 31; bool isq = tid >= 32;
    const float* src = lds2 + (isq?256:0);
    float tot=0.f;
#pragma unroll
    for (int sg=0;sg<8;++sg) tot += src[sg*32+j];
    atomicAdd(&S[shard*SHARD + offS + (isq?32:0) + j], tot);
  }
  __syncthreads();
}

// f32 column stats reduce (for pass1)
__device__ __forceinline__ void reduce_f32(const float* Xs, float* lds2,
                                           float* __restrict__ S, int offS, int shard)
{
  int tid = threadIdx.x;
  __syncthreads();
  {
    int j = tid & 31, seg = tid >> 5;
    float s=0.f, q=0.f;
    for (int q2=0;q2<32;++q2){
      float v = Xs[(seg*32+q2)*33 + j];
      s += v; q = fmaf(v,v,q);
    }
    lds2[seg*32+j] = s;
    lds2[256 + seg*32+j] = q;
  }
  __syncthreads();
  if (tid < 64){
    int j = tid & 31; bool isq = tid >= 32;
    const float* src = lds2 + (isq?256:0);
    float tot=0.f;
#pragma unroll
    for (int sg=0;sg<8;++sg) tot += src[sg*32+j];
    atomicAdd(&S[shard*SHARD + offS + (isq?32:0) + j], tot);
  }
  __syncthreads();
}

// ---------------- pass1: stats of o1, a1 (row per thread, fp32) ----------------
template<bool F32>
__device__ __forceinline__ void pass1_body(const void* __restrict__ u, const float* __restrict__ FW,
                                           float* __restrict__ S, float* Xs, float* lds2)
{
  int tid = threadIdx.x;
  int r = blockIdx.x*256 + tid;
  int shard = blockIdx.x & 3;
  float f[4]; load_u4<F32>(u,r,f);
  float* Xp = Xs + tid*33;
#pragma unroll
  for (int j=0;j<32;++j)
    Xp[j] = tanh_fast(FW[C1P+j] + f[0]*FW[FW1P+j] + f[1]*FW[FW1P+32+j] + f[2]*FW[FW1P+64+j] + f[3]*FW[FW1P+96+j]);
  reduce_f32(Xs, lds2, S, S_O1, shard);
#pragma unroll
  for (int j=0;j<32;++j)
    Xp[j] = tanh_fast(FW[C1O+j] + f[0]*FW[FW1O+j] + f[1]*FW[FW1O+32+j] + f[2]*FW[FW1O+64+j] + f[3]*FW[FW1O+96+j]);
  reduce_f32(Xs, lds2, S, S_A1, shard);
}
__global__ __launch_bounds__(256) void k_pass1(const void* __restrict__ u, const float* __restrict__ FW,
                                               float* __restrict__ S, const int* __restrict__ flag){
  __shared__ float Xs[256*33];
  __shared__ float lds2[512];
  if (*flag) pass1_body<true >(u,FW,S,Xs,lds2);
  else       pass1_body<false>(u,FW,S,Xs,lds2);
}

// ---------------- pass2: stats of o12 AND a2 via f16 MFMA ----------------
template<bool F32>
__device__ __forceinline__ void pass2_body(const void* __restrict__ u, const float* __restrict__ FW,
                                           float* __restrict__ S, u16* X, u16* Wt, float* Cb, float* lds2)
{
  int tid = threadIdx.x;
  int wv = tid >> 6, lane = tid & 63;
  int r = blockIdx.x*256 + tid;
  int shard = blockIdx.x & 3;
  // stage weights: L0 = 2P, L1 = 2O (transposed: Wt[n][k] = Wf[k*32+n])
  for (int i = tid; i < 2048; i += 256){
    int L = i >> 10, rem = i & 1023, k = rem >> 5, n = rem & 31;
    int base = L ? FW2O : FW2P;
    Wt[(L*32 + n)*XSTR + k] = f2h(FW[base + k*32 + n]);
  }
  if (tid < 64){
    int L = tid >> 5, n = tid & 31;
    Cb[tid] = FW[(L ? C2O : C2P) + n];
  }
  __syncthreads();

  float f[4]; load_u4<F32>(u,r,f);
  chain1_to_lds<true >(f, FW, X + tid*XSTR);              // o1
  mfma_layer<KIND_TANHRES>(X, Wt, Cb, 0, wv, lane, 0);    // o12 = o1 + tanh(.)
  reduce_f16(X, lds2, S, S_O12, shard);
  chain1_to_lds<false>(f, FW, X + tid*XSTR);              // a1
  mfma_layer<KIND_TANH  >(X, Wt, Cb, 1, wv, lane, 0);     // a2
  reduce_f16(X, lds2, S, S_A2, shard);
}
__global__ __launch_bounds__(256) void k_pass2(const void* __restrict__ u, const float* __restrict__ FW,
                                               float* __restrict__ S, const int* __restrict__ flag){
  __shared__ u16 X[256*XSTR];
  __shared__ u16 Wt[2*32*XSTR];
  __shared__ float Cb[64];
  __shared__ float lds2[512];
  if (*flag) pass2_body<true >(u,FW,S,X,Wt,Cb,lds2);
  else       pass2_body<false>(u,FW,S,X,Wt,Cb,lds2);
}

// ---------------- pass3: full chain via f16 MFMA + softmax + pooling + fused S_X ----------------
template<bool F32>
__device__ __forceinline__ void pass3_body(const void* __restrict__ u, const int* __restrict__ mask,
    const float* __restrict__ FW, float* __restrict__ x, float* __restrict__ S,
    u16* X, u16* AT, u16* Wt, float* Cb, float* red2)
{
  int tid = threadIdx.x;
  int wv = tid >> 6, lane = tid & 63;
  int r = blockIdx.x*256 + tid;
  // stage weights: L0=2O, L1=3O, L2=2P, L3=3P
  for (int i = tid; i < 4096; i += 256){
    int L = i >> 10, rem = i & 1023, k = rem >> 5, n = rem & 31;
    int base = (L==0)?FW2O : (L==1)?FW3O : (L==2)?FW2P : FW3P;
    Wt[(L*32 + n)*XSTR + k] = f2h(FW[base + k*32 + n]);
  }
  if (tid < 128){
    int L = tid >> 5, n = tid & 31;
    int base = (L==0)?C2O : (L==1)?C3O : (L==2)?C2P : C3P;
    Cb[tid] = FW[base + n];
  }
  __syncthreads();

  float f[4]; load_u4<F32>(u,r,f);

  // ---- omega chain ----
  chain1_to_lds<false>(f, FW, X + tid*XSTR);              // a1
  mfma_layer<KIND_TANH>(X, Wt, Cb, 0, wv, lane, 0);       // a2
  mfma_layer<KIND_NONE>(X, Wt, Cb, 1, wv, lane, 0);       // logits

  // ---- per-row softmax (+mask) -> AT ----
  {
    float lg[32];
#pragma unroll
    for (int c=0;c<4;++c){
      uint4 v = *(const uint4*)&X[tid*XSTR + c*8];
      lg[c*8+0]=lo16(v.x); lg[c*8+1]=hi16(v.x);
      lg[c*8+2]=lo16(v.y); lg[c*8+3]=hi16(v.y);
      lg[c*8+4]=lo16(v.z); lg[c*8+5]=hi16(v.z);
      lg[c*8+6]=lo16(v.w); lg[c*8+7]=hi16(v.w);
    }
    float mx = lg[0];
#pragma unroll
    for (int j=1;j<32;++j) mx = fmaxf(mx, lg[j]);
    float sum = 0.f;
#pragma unroll
    for (int j=0;j<32;++j){ float e = __expf(lg[j]-mx); lg[j]=e; sum+=e; }
    float inv = __builtin_amdgcn_rcpf(sum);
    bool mz = (mask[r] == 0);
#pragma unroll
    for (int j=0;j<32;++j){
      lg[j] *= inv;
      if (mz) lg[j] = -__builtin_inff();
    }
#pragma unroll
    for (int c=0;c<4;++c){
      uint4 v;
      v.x = pack2h(lg[c*8+0], lg[c*8+1]);
      v.y = pack2h(lg[c*8+2], lg[c*8+3]);
      v.z = pack2h(lg[c*8+4], lg[c*8+5]);
      v.w = pack2h(lg[c*8+6], lg[c*8+7]);
      *(uint4*)&AT[tid*XSTR + c*8] = v;
    }
  }

  // ---- phi chain ----
  chain1_to_lds<true>(f, FW, X + tid*XSTR);                    // o1
  mfma_layer<KIND_TANHRES   >(X, Wt, Cb, 2, wv, lane, 0);      // o12
  mfma_layer<KIND_TANHRES_AT>(X, Wt, Cb, 3, wv, lane, AT);     // xm * at

  // ---- pool over 128 neighbors (2 groups per block) + fused S_X ----
  __syncthreads();
  {
    int jj = tid & 31, cgrp = (tid >> 5) & 3, half = tid >> 7;
    float s2 = 0.f;
    for (int q2=0;q2<32;++q2) s2 += h2f(X[(half*128 + cgrp*32 + q2)*XSTR + jj]);
    red2[tid] = s2;
  }
  __syncthreads();
  if (tid < 64){
    int half = tid >> 5, j = tid & 31;
    float v = red2[half*128+j] + red2[half*128+32+j] + red2[half*128+64+j] + red2[half*128+96+j];
    x[(blockIdx.x*2 + half)*32 + j] = v;
    float* Sh = S + (blockIdx.x & 3)*SHARD;
    atomicAdd(&Sh[S_X+j], v);
    atomicAdd(&Sh[S_X+32+j], v*v);
  }
}
__global__ __launch_bounds__(256) void k_pass3(const void* __restrict__ u, const int* __restrict__ mask,
    const float* __restrict__ FW, float* __restrict__ x, float* __restrict__ S,
    const int* __restrict__ flag){
  __shared__ u16 X [256*XSTR];   // 20480 B
  __shared__ u16 AT[256*XSTR];   // 20480 B
  __shared__ u16 Wt[4*32*XSTR];  // 10240 B
  __shared__ float Cb[128];
  __shared__ float red2[256];
  if (*flag) pass3_body<true >(u,mask,FW,x,S,X,AT,Wt,Cb,red2);
  else       pass3_body<false>(u,mask,FW,x,S,X,AT,Wt,Cb,red2);
}

// ---------------- block-wide column reduce (blockDim==256) ----------------
__device__ __forceinline__ void block_reduce32(const float* vals, float* lds, float* __restrict__ dst){
  int t = threadIdx.x;
#pragma unroll
  for (int j=0;j<32;++j) lds[t*33+j] = vals[j];
  __syncthreads();
  if (t < 32){
    float tot=0.f;
    for (int q2=0;q2<256;++q2) tot += lds[q2*33+t];
    atomicAdd(&dst[t], tot);
  }
  __syncthreads();
}

// ---------------- theta layer (fp32 VALU; only 4096 rows) ----------------
template<bool F32>
__device__ __forceinline__ void theta_body(const float* __restrict__ X, float* __restrict__ S, int offin,
    const void* g, const void* bt, const void* W, float* __restrict__ Y, int offout, float* lds)
{
  int r = blockIdx.x*blockDim.x + threadIdx.x;   // 4096 rows exactly
  int tid = threadIdx.x;
  float* Xp = lds + tid*33;
#pragma unroll
  for (int k=0;k<32;++k){
    float m    = sumsh(S, offin+k)    * (1.0f/BROWS);
    float var  = sumsh(S, offin+32+k) * (1.0f/BROWS) - m*m;
    float rstd = rsqrtf(var + EPS);
    Xp[k] = (X[(size_t)r*32+k] - m) * (rdp<F32>(g,k)*rstd) + rdp<F32>(bt,k);
  }
  float out[32];
#pragma unroll
  for (int j=0;j<32;++j){
    float acc = 0.f;
#pragma unroll
    for (int k=0;k<32;++k) acc = fmaf(rdp<F32>(W, j*32+k), Xp[k], acc);
    out[j] = tanh_fast(acc);
    Y[(size_t)r*32+j] = out[j];
  }
  __syncthreads();
  float* Sh = S + (blockIdx.x & 3)*SHARD;
  block_reduce32(out, lds, Sh+offout);
#pragma unroll
  for (int j=0;j<32;++j) out[j] *= out[j];
  block_reduce32(out, lds, Sh+offout+32);
}
__global__ __launch_bounds__(256) void k_theta(const float* X, float* S, int offin,
    const void* g, const void* bt, const void* W, float* Y, int offout, const int* __restrict__ flag){
  __shared__ float lds[256*33];
  if (*flag) theta_body<true >(X,S,offin,g,bt,W,Y,offout,lds);
  else       theta_body<false>(X,S,offin,g,bt,W,Y,offout,lds);
}

// ---------------- final layer ----------------
template<bool F32>
__device__ __forceinline__ void theta4_body(const float* __restrict__ X, const float* __restrict__ S, int offin,
    const void* g, const void* bt, const void* w4, const void* b4, void* out)
{
  int r = blockIdx.x*blockDim.x + threadIdx.x;
  float acc = rdp<F32>(b4, 0);
#pragma unroll
  for (int k=0;k<32;++k){
    float m    = sumsh(S, offin+k)    * (1.0f/BROWS);
    float var  = sumsh(S, offin+32+k) * (1.0f/BROWS) - m*m;
    float rstd = rsqrtf(var + EPS);
    float xn = (X[(size_t)r*32+k] - m) * (rdp<F32>(g,k)*rstd) + rdp<F32>(bt,k);
    acc = fmaf(rdp<F32>(w4,k), xn, acc);
  }
  if (F32) ((float*)out)[r] = acc;
  else     ((u16*)out)[r]  = f2b(acc);
}
__global__ __launch_bounds__(256) void k_theta4(const float* X, const float* S, int offin,
    const void* g, const void* bt, const void* w4, const void* b4, void* out, const int* __restrict__ flag){
  if (*flag) theta4_body<true >(X,S,offin,g,bt,w4,b4,out);
  else       theta4_body<false>(X,S,offin,g,bt,w4,b4,out);
}

extern "C" void kernel_launch(void* const* d_in, const int* in_sizes, int n_in,
                              void* d_out, int out_size, void* d_ws, size_t ws_size,
                              hipStream_t stream)
{
  const void* u    = d_in[0];
  const int*  mask = (const int*)d_in[1];
  const void *pg1=d_in[2],  *pb1=d_in[3],  *pw1=d_in[4];
  const void *pg2=d_in[5],  *pb2=d_in[6],  *pw2=d_in[7];
  const void *pg3=d_in[8],  *pb3=d_in[9],  *pw3=d_in[10];
  const void *og1=d_in[11], *ob1=d_in[12], *ow1=d_in[13];
  const void *og2=d_in[14], *ob2=d_in[15], *ow2=d_in[16];
  const void *og3=d_in[17], *ob3=d_in[18], *ow3=d_in[19];
  const void *tg1=d_in[20], *tb1=d_in[21], *tw1=d_in[22];
  const void *tg2=d_in[23], *tb2=d_in[24], *tw2=d_in[25];
  const void *tg3=d_in[26], *tb3=d_in[27], *tw3=d_in[28];
  const void *tg4=d_in[29], *tb4=d_in[30], *tw4=d_in[31], *tbb4=d_in[32];

  char* ws = (char*)d_ws;
  int*   flag = (int*)ws;                    // byte 0
  float* S    = (float*)(ws + 1024);         // 4 shards x 1024 floats = 16 KB
  float* FW   = (float*)(ws + 20480);        // 4544 floats
  float* x    = (float*)(ws + 65536);        // 4096*32 f32
  float* x1 = x  + BROWS*32;
  float* x2 = x1 + BROWS*32;
  float* x3 = x2 + BROWS*32;

  (void)hipMemsetAsync(ws, 0, 20480, stream);  // zero flag + sharded stats
  k_detect<<<1, 64, 0, stream>>>((const u16*)u, flag);
  k_stats_u<<<512, 256, 0, stream>>>(u, S, flag);
  k_foldL1<<<1, 64, 0, stream>>>(S, FW, pg1,pb1,pw1, og1,ob1,ow1, flag);
  k_pass1<<<2048, 256, 0, stream>>>(u, FW, S, flag);
  k_foldL<<<1, 64, 0, stream>>>(S, S_O1, S_A1, FW, FW2P, C2P, FW2O, C2O,
                                pg2,pb2,pw2, og2,ob2,ow2, flag);
  k_pass2<<<2048, 256, 0, stream>>>(u, FW, S, flag);
  k_foldL<<<1, 64, 0, stream>>>(S, S_O12, S_A2, FW, FW3P, C3P, FW3O, C3O,
                                pg3,pb3,pw3, og3,ob3,ow3, flag);
  k_pass3<<<2048, 256, 0, stream>>>(u, mask, FW, x, S, flag);
  k_theta<<<16, 256, 0, stream>>>(x,  S, S_X,  tg1,tb1,tw1, x1, S_X1, flag);
  k_theta<<<16, 256, 0, stream>>>(x1, S, S_X1, tg2,tb2,tw2, x2, S_X2, flag);
  k_theta<<<16, 256, 0, stream>>>(x2, S, S_X2, tg3,tb3,tw3, x3, S_X3, flag);
  k_theta4<<<16, 256, 0, stream>>>(x3, S, S_X3, tg4,tb4,tw4,tbb4, d_out, flag);
}

// Round 10
// 439.177 us; speedup vs baseline: 1.1870x; 1.0483x over previous
//
#include <hip/hip_runtime.h>

typedef unsigned int u32;
typedef unsigned short u16;
typedef __attribute__((ext_vector_type(8))) _Float16 half8;
typedef __attribute__((ext_vector_type(4))) float f32x4;

#define ROWS  524288   // B*N
#define BROWS 4096     // B
#define EPS   1e-5f

// ---- stats: 4 shards of 1024 floats each; consumers sum shards ----
#define S_U   0
#define S_O1  8
#define S_A1  72
#define S_O12 136
#define S_A2  200
#define S_X   264
#define S_X1  328
#define S_X2  392
#define S_X3  456
#define SHARD 1024

#define XSTR 40   // LDS row stride in u16: 80 B -> 16-B aligned b128, conflict-friendly

__device__ __forceinline__ float bl(u32 u){ return __uint_as_float(u << 16); }
__device__ __forceinline__ float bh(u32 u){ return __uint_as_float(u & 0xFFFF0000u); }
__device__ __forceinline__ float b2f(u16 h){ return __uint_as_float(((u32)h) << 16); }
__device__ __forceinline__ u16 f2b(float f){
  u32 u = __float_as_uint(f);
  return (u16)((u + 0x7FFFu + ((u >> 16) & 1u)) >> 16);   // RNE (bf16, output only)
}
__device__ __forceinline__ u16 f2h(float f){ _Float16 h = (_Float16)f; return __builtin_bit_cast(u16, h); }
__device__ __forceinline__ float h2f(u16 x){ return (float)__builtin_bit_cast(_Float16, x); }
__device__ __forceinline__ u32 pack2h(float a, float b){
  auto v = __builtin_amdgcn_cvt_pkrtz(a, b);
  return __builtin_bit_cast(u32, v);
}
__device__ __forceinline__ float lo16(u32 w){ return h2f((u16)(w & 0xFFFF)); }
__device__ __forceinline__ float hi16(u32 w){ return h2f((u16)(w >> 16)); }
__device__ __forceinline__ void unpk4(uint2 v, float* d){
  d[0]=lo16(v.x); d[1]=hi16(v.x); d[2]=lo16(v.y); d[3]=hi16(v.y);
}

__device__ __forceinline__ float tanh_fast(float x){
  float e = __expf(2.0f * x);
  return 1.0f - 2.0f * __builtin_amdgcn_rcpf(e + 1.0f);
}
__device__ __forceinline__ float sumsh(const float* __restrict__ S, int off){
  return S[off] + S[SHARD+off] + S[2*SHARD+off] + S[3*SHARD+off];
}

template<bool F32>
__device__ __forceinline__ float rdp(const void* p, int i){
  if (F32) return ((const float*)p)[i];
  return b2f(((const u16*)p)[i]);
}
template<bool F32>
__device__ __forceinline__ void load_u4(const void* u, int r, float* f){
  if (F32){
    float4 v = ((const float4*)u)[r];
    f[0]=v.x; f[1]=v.y; f[2]=v.z; f[3]=v.w;
  } else {
    uint2 v = ((const uint2*)u)[r];
    f[0]=bl(v.x); f[1]=bh(v.x); f[2]=bl(v.y); f[3]=bh(v.y);
  }
}

// ---------------- dtype detection ----------------
__global__ void k_detect(const u16* __restrict__ u, int* __restrict__ flag){
  int t = threadIdx.x;   // 64
  int bad = 0;
  for (int i = t*4; i < t*4+4; ++i){
    int e = (u[i] >> 7) & 0xFF;
    bad += (e >= 0x90) ? 1 : 0;
  }
#pragma unroll
  for (int off = 32; off >= 1; off >>= 1) bad += __shfl_down(bad, off);
  if (t == 0) *flag = (bad >= 4) ? 1 : 0;
}

// ---------------- stats of u (4 cols) ----------------
template<bool F32>
__device__ __forceinline__ void stats_u_body(const void* __restrict__ u, float* __restrict__ S){
  int tid = blockIdx.x*blockDim.x + threadIdx.x;
  int nt  = gridDim.x*blockDim.x;
  float s[4]={0,0,0,0}, q[4]={0,0,0,0};
  for (int r = tid; r < ROWS; r += nt){
    float f[4]; load_u4<F32>(u, r, f);
#pragma unroll
    for (int k=0;k<4;++k){ s[k]+=f[k]; q[k]+=f[k]*f[k]; }
  }
#pragma unroll
  for (int off=32; off>=1; off>>=1){
#pragma unroll
    for (int k=0;k<4;++k){ s[k]+=__shfl_down(s[k],off); q[k]+=__shfl_down(q[k],off); }
  }
  if ((threadIdx.x & 63) == 0){
    float* Sh = S + (blockIdx.x & 3)*SHARD;
#pragma unroll
    for (int k=0;k<4;++k){ atomicAdd(&Sh[S_U+k], s[k]); atomicAdd(&Sh[S_U+4+k], q[k]); }
  }
}
__global__ __launch_bounds__(256) void k_stats_u(const void* __restrict__ u, float* __restrict__ S,
                                                 const int* __restrict__ flag){
  if (*flag) stats_u_body<true>(u,S); else stats_u_body<false>(u,S);
}

// ---------------- BN of u inputs: xn[k] = (f[k]-m)*g*rstd + b ----------------
template<bool F32>
__device__ __forceinline__ void bn_u(const float* __restrict__ S, const void* g, const void* b,
                                     const float* f, float* xn){
#pragma unroll
  for (int k=0;k<4;++k){
    float m    = sumsh(S, S_U+k)  *(1.0f/ROWS);
    float var  = sumsh(S, S_U+4+k)*(1.0f/ROWS) - m*m;
    float rstd = rsqrtf(var + EPS);
    xn[k] = (f[k]-m)*(rdp<F32>(g,k)*rstd) + rdp<F32>(b,k);
  }
}

// ---------------- L1 chain: o1[j] = tanh(sum_k xn[k]*W1[j][k]) -> f16 LDS row ----------------
template<bool F32>
__device__ __forceinline__ void chain1_to_lds(const float* xn, const void* W1, u16* Xrow){
  u32 buf[16];
#pragma unroll
  for (int jp=0; jp<16; ++jp){
    int j0 = 2*jp, j1 = 2*jp+1;
    float a0 = tanh_fast(xn[0]*rdp<F32>(W1,j0*4+0) + xn[1]*rdp<F32>(W1,j0*4+1)
                       + xn[2]*rdp<F32>(W1,j0*4+2) + xn[3]*rdp<F32>(W1,j0*4+3));
    float a1 = tanh_fast(xn[0]*rdp<F32>(W1,j1*4+0) + xn[1]*rdp<F32>(W1,j1*4+1)
                       + xn[2]*rdp<F32>(W1,j1*4+2) + xn[3]*rdp<F32>(W1,j1*4+3));
    buf[jp] = pack2h(a0, a1);
  }
#pragma unroll
  for (int c=0;c<4;++c){
    uint4 v; v.x = buf[c*4]; v.y = buf[c*4+1]; v.z = buf[c*4+2]; v.w = buf[c*4+3];
    *(uint4*)&Xrow[c*8] = v;
  }
}

// ---------------- in-block BN+Linear fold: 2 layers -> Wt (f16 A-layout) + Cb ----------------
// Deterministic from S -> bit-identical across blocks (pass2/pass3 consistency).
template<bool F32>
__device__ __forceinline__ void fold2(const float* __restrict__ S, int offA, int offB,
    const void* gA, const void* bA, const void* WA,
    const void* gB, const void* bB, const void* WB,
    u16* Wt, float* Cb, float* scr /* >=128 floats */)
{
  int tid = threadIdx.x;
  if (tid < 64){
    int L = tid>>5, k = tid&31;
    const void* g = L? gB:gA; const void* b = L? bB:bA;
    int off = L? offB:offA;
    float m    = sumsh(S, off+k)   *(1.0f/ROWS);
    float var  = sumsh(S, off+32+k)*(1.0f/ROWS) - m*m;
    float rstd = rsqrtf(var+EPS);
    float sc = rdp<F32>(g,k)*rstd;
    scr[tid]    = sc;
    scr[64+tid] = rdp<F32>(b,k) - m*sc;
  }
  __syncthreads();
  if (tid < 64){
    int L = tid>>5, j = tid&31;
    const void* W = L? WB:WA;
    float c = 0.f;
#pragma unroll
    for (int k=0;k<32;++k){
      float Wv = rdp<F32>(W, j*32+k);
      Wt[(L*32+j)*XSTR + k] = f2h(Wv * scr[(L<<5)|k]);
      c += Wv * scr[64 + ((L<<5)|k)];
    }
    Cb[L*32+j] = c;
  }
  __syncthreads();
}

// 4-layer variant (pass3): L0,L1,L2,L3; scr >= 256 floats
template<bool F32>
__device__ __forceinline__ void fold4(const float* __restrict__ S,
    int off0,int off1,int off2,int off3,
    const void* g0,const void* b0,const void* W0,
    const void* g1,const void* b1,const void* W1,
    const void* g2,const void* b2,const void* W2,
    const void* g3,const void* b3,const void* W3,
    u16* Wt, float* Cb, float* scr)
{
  int tid = threadIdx.x;
  if (tid < 128){
    int L = tid>>5, k = tid&31;
    const void* g = (L==0)?g0:(L==1)?g1:(L==2)?g2:g3;
    const void* b = (L==0)?b0:(L==1)?b1:(L==2)?b2:b3;
    int off = (L==0)?off0:(L==1)?off1:(L==2)?off2:off3;
    float m    = sumsh(S, off+k)   *(1.0f/ROWS);
    float var  = sumsh(S, off+32+k)*(1.0f/ROWS) - m*m;
    float rstd = rsqrtf(var+EPS);
    float sc = rdp<F32>(g,k)*rstd;
    scr[tid]     = sc;
    scr[128+tid] = rdp<F32>(b,k) - m*sc;
  }
  __syncthreads();
  if (tid < 128){
    int L = tid>>5, j = tid&31;
    const void* W = (L==0)?W0:(L==1)?W1:(L==2)?W2:W3;
    float c = 0.f;
#pragma unroll
    for (int k=0;k<32;++k){
      float Wv = rdp<F32>(W, j*32+k);
      Wt[(L*32+j)*XSTR + k] = f2h(Wv * scr[(L<<5)|k]);
      c += Wv * scr[128 + (L<<5) + k];
    }
    Cb[L*32+j] = c;
  }
  __syncthreads();
}

// ---------------- one 32x32 layer: Y^T = W.X^T via mfma_f32_16x16x32_f16 ----------------
// A = weights (m=feature out, k=feature in), B = X rows (n=sample), C: col=sample, row=feature.
// Epilogue: 4 consecutive features per lane -> b64 LDS ops (no scalar u16 traffic).
#define KIND_TANH       0
#define KIND_NONE       1
#define KIND_TANHRES    2
#define KIND_TANHRES_AT 3
template<int KIND>
__device__ __forceinline__ void mfma_layer(u16* X, const u16* Wt, const float* Cb,
                                           int L, int wv, int lane, const u16* AT)
{
  int ln15 = lane & 15, quad = lane >> 4;
  half8 w0 = *(const half8*)&Wt[(L*32 + ln15     )*XSTR + quad*8];
  half8 w1 = *(const half8*)&Wt[(L*32 + ln15 + 16)*XSTR + quad*8];
  float bias0[4], bias1[4];
#pragma unroll
  for (int reg=0;reg<4;++reg){
    bias0[reg] = Cb[L*32 +      quad*4 + reg];
    bias1[reg] = Cb[L*32 + 16 + quad*4 + reg];
  }
  int rowbase = wv*64;
#pragma unroll
  for (int Mt=0; Mt<4; ++Mt){
    int s = rowbase + Mt*16 + ln15;          // this lane's sample
    half8 bfr = *(const half8*)&X[s*XSTR + quad*8];
    f32x4 c0 = {0.f,0.f,0.f,0.f}, c1 = {0.f,0.f,0.f,0.f};
    c0 = __builtin_amdgcn_mfma_f32_16x16x32_f16(w0, bfr, c0, 0,0,0);
    c1 = __builtin_amdgcn_mfma_f32_16x16x32_f16(w1, bfr, c1, 0,0,0);
    float o0[4], o1v[4], t0[4], t1[4];
    if (KIND == KIND_TANHRES || KIND == KIND_TANHRES_AT){
      unpk4(*(const uint2*)&X[s*XSTR +      quad*4], o0);
      unpk4(*(const uint2*)&X[s*XSTR + 16 + quad*4], o1v);
    }
    if (KIND == KIND_TANHRES_AT){
      unpk4(*(const uint2*)&AT[s*XSTR +      quad*4], t0);
      unpk4(*(const uint2*)&AT[s*XSTR + 16 + quad*4], t1);
    }
    float v0[4], v1[4];
#pragma unroll
    for (int reg=0;reg<4;++reg){
      float a = c0[reg] + bias0[reg];
      float b = c1[reg] + bias1[reg];
      if (KIND == KIND_TANH){ a = tanh_fast(a); b = tanh_fast(b); }
      else if (KIND == KIND_TANHRES){ a = o0[reg] + tanh_fast(a); b = o1v[reg] + tanh_fast(b); }
      else if (KIND == KIND_TANHRES_AT){
        a = (o0[reg] + tanh_fast(a)) * t0[reg];
        b = (o1v[reg] + tanh_fast(b)) * t1[reg];
      }
      v0[reg] = a; v1[reg] = b;
    }
    uint2 w0o, w1o;
    w0o.x = pack2h(v0[0], v0[1]); w0o.y = pack2h(v0[2], v0[3]);
    w1o.x = pack2h(v1[0], v1[1]); w1o.y = pack2h(v1[2], v1[3]);
    *(uint2*)&X[s*XSTR +      quad*4] = w0o;
    *(uint2*)&X[s*XSTR + 16 + quad*4] = w1o;
  }
}

// ---------------- column stats of 256x32 f16 tile -> sharded atomics ----------------
__device__ __forceinline__ void reduce_f16(const u16* X, float* lds2,
                                           float* __restrict__ S, int offS, int shard)
{
  int tid = threadIdx.x;
  __syncthreads();
  {
    int j = tid & 31, seg = tid >> 5;
    float s=0.f, q=0.f;
    for (int q2=0;q2<32;++q2){
      float v = h2f(X[(seg*32+q2)*XSTR + j]);
      s += v; q = fmaf(v,v,q);
    }
    lds2[seg*32+j] = s;
    lds2[256 + seg*32+j] = q;
  }
  __syncthreads();
  if (tid < 64){
    int j = tid & 31; bool isq = tid >= 32;
    const float* src = lds2 + (isq?256:0);
    float tot=0.f;
#pragma unroll
    for (int sg=0;sg<8;++sg) tot += src[sg*32+j];
    atomicAdd(&S[shard*SHARD + offS + (isq?32:0) + j], tot);
  }
  __syncthreads();
}

__device__ __forceinline__ void reduce_f32(const float* Xs, float* lds2,
                                           float* __restrict__ S, int offS, int shard)
{
  int tid = threadIdx.x;
  __syncthreads();
  {
    int j = tid & 31, seg = tid >> 5;
    float s=0.f, q=0.f;
    for (int q2=0;q2<32;++q2){
      float v = Xs[(seg*32+q2)*33 + j];
      s += v; q = fmaf(v,v,q);
    }
    lds2[seg*32+j] = s;
    lds2[256 + seg*32+j] = q;
  }
  __syncthreads();
  if (tid < 64){
    int j = tid & 31; bool isq = tid >= 32;
    const float* src = lds2 + (isq?256:0);
    float tot=0.f;
#pragma unroll
    for (int sg=0;sg<8;++sg) tot += src[sg*32+j];
    atomicAdd(&S[shard*SHARD + offS + (isq?32:0) + j], tot);
  }
  __syncthreads();
}

// ---------------- pass1: stats of o1, a1 (row/thread, raw weights + BN'd inputs) ----------------
template<bool F32>
__device__ __forceinline__ void pass1_body(const void* __restrict__ u,
    const void* pg1, const void* pb1, const void* pw1,
    const void* og1, const void* ob1, const void* ow1,
    float* __restrict__ S, float* Xs, float* lds2)
{
  int tid = threadIdx.x;
  int r = blockIdx.x*256 + tid;
  int shard = blockIdx.x & 3;
  float f[4]; load_u4<F32>(u,r,f);
  float xn[4];
  float* Xp = Xs + tid*33;
  bn_u<F32>(S, pg1, pb1, f, xn);
#pragma unroll
  for (int j=0;j<32;++j)
    Xp[j] = tanh_fast(xn[0]*rdp<F32>(pw1,j*4+0) + xn[1]*rdp<F32>(pw1,j*4+1)
                    + xn[2]*rdp<F32>(pw1,j*4+2) + xn[3]*rdp<F32>(pw1,j*4+3));
  reduce_f32(Xs, lds2, S, S_O1, shard);
  bn_u<F32>(S, og1, ob1, f, xn);
#pragma unroll
  for (int j=0;j<32;++j)
    Xp[j] = tanh_fast(xn[0]*rdp<F32>(ow1,j*4+0) + xn[1]*rdp<F32>(ow1,j*4+1)
                    + xn[2]*rdp<F32>(ow1,j*4+2) + xn[3]*rdp<F32>(ow1,j*4+3));
  reduce_f32(Xs, lds2, S, S_A1, shard);
}
__global__ __launch_bounds__(256) void k_pass1(const void* __restrict__ u,
    const void* pg1, const void* pb1, const void* pw1,
    const void* og1, const void* ob1, const void* ow1,
    float* __restrict__ S, const int* __restrict__ flag){
  __shared__ float Xs[256*33];
  __shared__ float lds2[512];
  if (*flag) pass1_body<true >(u,pg1,pb1,pw1,og1,ob1,ow1,S,Xs,lds2);
  else       pass1_body<false>(u,pg1,pb1,pw1,og1,ob1,ow1,S,Xs,lds2);
}

// ---------------- pass2: stats of o12 AND a2 via f16 MFMA (in-block fold) ----------------
template<bool F32>
__device__ __forceinline__ void pass2_body(const void* __restrict__ u,
    const void* pg1, const void* pb1, const void* pw1,
    const void* og1, const void* ob1, const void* ow1,
    const void* pg2, const void* pb2, const void* pw2,
    const void* og2, const void* ob2, const void* ow2,
    float* __restrict__ S, u16* X, u16* Wt, float* Cb, float* lds2)
{
  int tid = threadIdx.x;
  int wv = tid >> 6, lane = tid & 63;
  int r = blockIdx.x*256 + tid;
  int shard = blockIdx.x & 3;
  // fold L0 = 2P (S_O1), L1 = 2O (S_A1)
  fold2<F32>(S, S_O1, S_A1, pg2,pb2,pw2, og2,ob2,ow2, Wt, Cb, lds2);

  float f[4]; load_u4<F32>(u,r,f);
  float xn[4];
  bn_u<F32>(S, pg1, pb1, f, xn);
  chain1_to_lds<F32>(xn, pw1, X + tid*XSTR);              // o1
  mfma_layer<KIND_TANHRES>(X, Wt, Cb, 0, wv, lane, 0);    // o12 = o1 + tanh(.)
  reduce_f16(X, lds2, S, S_O12, shard);
  bn_u<F32>(S, og1, ob1, f, xn);
  chain1_to_lds<F32>(xn, ow1, X + tid*XSTR);              // a1
  mfma_layer<KIND_TANH  >(X, Wt, Cb, 1, wv, lane, 0);     // a2
  reduce_f16(X, lds2, S, S_A2, shard);
}
__global__ __launch_bounds__(256) void k_pass2(const void* __restrict__ u,
    const void* pg1, const void* pb1, const void* pw1,
    const void* og1, const void* ob1, const void* ow1,
    const void* pg2, const void* pb2, const void* pw2,
    const void* og2, const void* ob2, const void* ow2,
    float* __restrict__ S, const int* __restrict__ flag){
  __shared__ u16 X[256*XSTR];      // 20480 B
  __shared__ u16 Wt[2*32*XSTR];    //  5120 B
  __shared__ float Cb[64];
  __shared__ float lds2[512];
  if (*flag) pass2_body<true >(u,pg1,pb1,pw1,og1,ob1,ow1,pg2,pb2,pw2,og2,ob2,ow2,S,X,Wt,Cb,lds2);
  else       pass2_body<false>(u,pg1,pb1,pw1,og1,ob1,ow1,pg2,pb2,pw2,og2,ob2,ow2,S,X,Wt,Cb,lds2);
}

// ---------------- pass3: full chain + softmax + pooling + fused S_X ----------------
template<bool F32>
__device__ __forceinline__ void pass3_body(const void* __restrict__ u, const int* __restrict__ mask,
    const void* pg1, const void* pb1, const void* pw1,
    const void* og1, const void* ob1, const void* ow1,
    const void* pg2, const void* pb2, const void* pw2,
    const void* og2, const void* ob2, const void* ow2,
    const void* pg3, const void* pb3, const void* pw3,
    const void* og3, const void* ob3, const void* ow3,
    float* __restrict__ x, float* __restrict__ S,
    u16* X, u16* AT, u16* Wt, float* Cb, float* red2)
{
  int tid = threadIdx.x;
  int wv = tid >> 6, lane = tid & 63;
  int r = blockIdx.x*256 + tid;
  // fold L0=2O(S_A1), L1=3O(S_A2), L2=2P(S_O1), L3=3P(S_O12); red2 as 256-float scratch
  fold4<F32>(S, S_A1, S_A2, S_O1, S_O12,
             og2,ob2,ow2, og3,ob3,ow3, pg2,pb2,pw2, pg3,pb3,pw3,
             Wt, Cb, red2);

  float f[4]; load_u4<F32>(u,r,f);
  float xn[4];

  // ---- omega chain ----
  bn_u<F32>(S, og1, ob1, f, xn);
  chain1_to_lds<F32>(xn, ow1, X + tid*XSTR);              // a1
  mfma_layer<KIND_TANH>(X, Wt, Cb, 0, wv, lane, 0);       // a2
  mfma_layer<KIND_NONE>(X, Wt, Cb, 1, wv, lane, 0);       // logits

  // ---- per-row softmax (+mask) -> AT ----
  {
    float lg[32];
#pragma unroll
    for (int c=0;c<4;++c){
      uint4 v = *(const uint4*)&X[tid*XSTR + c*8];
      lg[c*8+0]=lo16(v.x); lg[c*8+1]=hi16(v.x);
      lg[c*8+2]=lo16(v.y); lg[c*8+3]=hi16(v.y);
      lg[c*8+4]=lo16(v.z); lg[c*8+5]=hi16(v.z);
      lg[c*8+6]=lo16(v.w); lg[c*8+7]=hi16(v.w);
    }
    float mx = lg[0];
#pragma unroll
    for (int j=1;j<32;++j) mx = fmaxf(mx, lg[j]);
    float sum = 0.f;
#pragma unroll
    for (int j=0;j<32;++j){ float e = __expf(lg[j]-mx); lg[j]=e; sum+=e; }
    float inv = __builtin_amdgcn_rcpf(sum);
    bool mz = (mask[r] == 0);
#pragma unroll
    for (int j=0;j<32;++j){
      lg[j] *= inv;
      if (mz) lg[j] = -__builtin_inff();
    }
#pragma unroll
    for (int c=0;c<4;++c){
      uint4 v;
      v.x = pack2h(lg[c*8+0], lg[c*8+1]);
      v.y = pack2h(lg[c*8+2], lg[c*8+3]);
      v.z = pack2h(lg[c*8+4], lg[c*8+5]);
      v.w = pack2h(lg[c*8+6], lg[c*8+7]);
      *(uint4*)&AT[tid*XSTR + c*8] = v;
    }
  }

  // ---- phi chain ----
  bn_u<F32>(S, pg1, pb1, f, xn);
  chain1_to_lds<F32>(xn, pw1, X + tid*XSTR);                   // o1
  mfma_layer<KIND_TANHRES   >(X, Wt, Cb, 2, wv, lane, 0);      // o12
  mfma_layer<KIND_TANHRES_AT>(X, Wt, Cb, 3, wv, lane, AT);     // xm * at

  // ---- pool over 128 neighbors (2 groups per block) + fused S_X ----
  __syncthreads();
  {
    int jj = tid & 31, cgrp = (tid >> 5) & 3, half = tid >> 7;
    float s2 = 0.f;
    for (int q2=0;q2<32;++q2) s2 += h2f(X[(half*128 + cgrp*32 + q2)*XSTR + jj]);
    red2[tid] = s2;
  }
  __syncthreads();
  if (tid < 64){
    int half = tid >> 5, j = tid & 31;
    float v = red2[half*128+j] + red2[half*128+32+j] + red2[half*128+64+j] + red2[half*128+96+j];
    x[(blockIdx.x*2 + half)*32 + j] = v;
    float* Sh = S + (blockIdx.x & 3)*SHARD;
    atomicAdd(&Sh[S_X+j], v);
    atomicAdd(&Sh[S_X+32+j], v*v);
  }
}
__global__ __launch_bounds__(256) void k_pass3(const void* __restrict__ u, const int* __restrict__ mask,
    const void* pg1, const void* pb1, const void* pw1,
    const void* og1, const void* ob1, const void* ow1,
    const void* pg2, const void* pb2, const void* pw2,
    const void* og2, const void* ob2, const void* ow2,
    const void* pg3, const void* pb3, const void* pw3,
    const void* og3, const void* ob3, const void* ow3,
    float* __restrict__ x, float* __restrict__ S, const int* __restrict__ flag){
  __shared__ u16 X [256*XSTR];   // 20480 B
  __shared__ u16 AT[256*XSTR];   // 20480 B
  __shared__ u16 Wt[4*32*XSTR];  // 10240 B
  __shared__ float Cb[128];      //   512 B
  __shared__ float red2[256];    //  1024 B  (also fold scratch)
  if (*flag) pass3_body<true >(u,mask,pg1,pb1,pw1,og1,ob1,ow1,pg2,pb2,pw2,og2,ob2,ow2,
                               pg3,pb3,pw3,og3,ob3,ow3,x,S,X,AT,Wt,Cb,red2);
  else       pass3_body<false>(u,mask,pg1,pb1,pw1,og1,ob1,ow1,pg2,pb2,pw2,og2,ob2,ow2,
                               pg3,pb3,pw3,og3,ob3,ow3,x,S,X,AT,Wt,Cb,red2);
}

// ---------------- block-wide column reduce (blockDim==256) ----------------
__device__ __forceinline__ void block_reduce32(const float* vals, float* lds, float* __restrict__ dst){
  int t = threadIdx.x;
#pragma unroll
  for (int j=0;j<32;++j) lds[t*33+j] = vals[j];
  __syncthreads();
  if (t < 32){
    float tot=0.f;
    for (int q2=0;q2<256;++q2) tot += lds[q2*33+t];
    atomicAdd(&dst[t], tot);
  }
  __syncthreads();
}

// ---------------- theta layer (fp32 VALU; only 4096 rows) ----------------
template<bool F32>
__device__ __forceinline__ void theta_body(const float* __restrict__ X, float* __restrict__ S, int offin,
    const void* g, const void* bt, const void* W, float* __restrict__ Y, int offout, float* lds)
{
  int r = blockIdx.x*blockDim.x + threadIdx.x;   // 4096 rows exactly
  int tid = threadIdx.x;
  float* Xp = lds + tid*33;
#pragma unroll
  for (int k=0;k<32;++k){
    float m    = sumsh(S, offin+k)    * (1.0f/BROWS);
    float var  = sumsh(S, offin+32+k) * (1.0f/BROWS) - m*m;
    float rstd = rsqrtf(var + EPS);
    Xp[k] = (X[(size_t)r*32+k] - m) * (rdp<F32>(g,k)*rstd) + rdp<F32>(bt,k);
  }
  float out[32];
#pragma unroll
  for (int j=0;j<32;++j){
    float acc = 0.f;
#pragma unroll
    for (int k=0;k<32;++k) acc = fmaf(rdp<F32>(W, j*32+k), Xp[k], acc);
    out[j] = tanh_fast(acc);
    Y[(size_t)r*32+j] = out[j];
  }
  __syncthreads();
  float* Sh = S + (blockIdx.x & 3)*SHARD;
  block_reduce32(out, lds, Sh+offout);
#pragma unroll
  for (int j=0;j<32;++j) out[j] *= out[j];
  block_reduce32(out, lds, Sh+offout+32);
}
__global__ __launch_bounds__(256) void k_theta(const float* X, float* S, int offin,
    const void* g, const void* bt, const void* W, float* Y, int offout, const int* __restrict__ flag){
  __shared__ float lds[256*33];
  if (*flag) theta_body<true >(X,S,offin,g,bt,W,Y,offout,lds);
  else       theta_body<false>(X,S,offin,g,bt,W,Y,offout,lds);
}

// ---------------- final layer ----------------
template<bool F32>
__device__ __forceinline__ void theta4_body(const float* __restrict__ X, const float* __restrict__ S, int offin,
    const void* g, const void* bt, const void* w4, const void* b4, void* out)
{
  int r = blockIdx.x*blockDim.x + threadIdx.x;
  float acc = rdp<F32>(b4, 0);
#pragma unroll
  for (int k=0;k<32;++k){
    float m    = sumsh(S, offin+k)    * (1.0f/BROWS);
    float var  = sumsh(S, offin+32+k) * (1.0f/BROWS) - m*m;
    float rstd = rsqrtf(var + EPS);
    float xnv = (X[(size_t)r*32+k] - m) * (rdp<F32>(g,k)*rstd) + rdp<F32>(bt,k);
    acc = fmaf(rdp<F32>(w4,k), xnv, acc);
  }
  if (F32) ((float*)out)[r] = acc;
  else     ((u16*)out)[r]  = f2b(acc);
}
__global__ __launch_bounds__(256) void k_theta4(const float* X, const float* S, int offin,
    const void* g, const void* bt, const void* w4, const void* b4, void* out, const int* __restrict__ flag){
  if (*flag) theta4_body<true >(X,S,offin,g,bt,w4,b4,out);
  else       theta4_body<false>(X,S,offin,g,bt,w4,b4,out);
}

extern "C" void kernel_launch(void* const* d_in, const int* in_sizes, int n_in,
                              void* d_out, int out_size, void* d_ws, size_t ws_size,
                              hipStream_t stream)
{
  const void* u    = d_in[0];
  const int*  mask = (const int*)d_in[1];
  const void *pg1=d_in[2],  *pb1=d_in[3],  *pw1=d_in[4];
  const void *pg2=d_in[5],  *pb2=d_in[6],  *pw2=d_in[7];
  const void *pg3=d_in[8],  *pb3=d_in[9],  *pw3=d_in[10];
  const void *og1=d_in[11], *ob1=d_in[12], *ow1=d_in[13];
  const void *og2=d_in[14], *ob2=d_in[15], *ow2=d_in[16];
  const void *og3=d_in[17], *ob3=d_in[18], *ow3=d_in[19];
  const void *tg1=d_in[20], *tb1=d_in[21], *tw1=d_in[22];
  const void *tg2=d_in[23], *tb2=d_in[24], *tw2=d_in[25];
  const void *tg3=d_in[26], *tb3=d_in[27], *tw3=d_in[28];
  const void *tg4=d_in[29], *tb4=d_in[30], *tw4=d_in[31], *tbb4=d_in[32];

  char* ws = (char*)d_ws;
  int*   flag = (int*)ws;                    // byte 0
  float* S    = (float*)(ws + 1024);         // 4 shards x 1024 floats = 16 KB
  float* x    = (float*)(ws + 65536);        // 4096*32 f32
  float* x1 = x  + BROWS*32;
  float* x2 = x1 + BROWS*32;
  float* x3 = x2 + BROWS*32;

  (void)hipMemsetAsync(ws, 0, 20480, stream);  // zero flag + sharded stats
  k_detect<<<1, 64, 0, stream>>>((const u16*)u, flag);
  k_stats_u<<<512, 256, 0, stream>>>(u, S, flag);
  k_pass1<<<2048, 256, 0, stream>>>(u, pg1,pb1,pw1, og1,ob1,ow1, S, flag);
  k_pass2<<<2048, 256, 0, stream>>>(u, pg1,pb1,pw1, og1,ob1,ow1,
                                    pg2,pb2,pw2, og2,ob2,ow2, S, flag);
  k_pass3<<<2048, 256, 0, stream>>>(u, mask, pg1,pb1,pw1, og1,ob1,ow1,
                                    pg2,pb2,pw2, og2,ob2,ow2,
                                    pg3,pb3,pw3, og3,ob3,ow3, x, S, flag);
  k_theta<<<16, 256, 0, stream>>>(x,  S, S_X,  tg1,tb1,tw1, x1, S_X1, flag);
  k_theta<<<16, 256, 0, stream>>>(x1, S, S_X1, tg2,tb2,tw2, x2, S_X2, flag);
  k_theta<<<16, 256, 0, stream>>>(x2, S, S_X2, tg3,tb3,tw3, x3, S_X3, flag);
  k_theta4<<<16, 256, 0, stream>>>(x3, S, S_X3, tg4,tb4,tw4,tbb4, d_out, flag);
}